// Round 4
// baseline (991.282 us; speedup 1.0000x reference)
//
#include <hip/hip_runtime.h>
#include <cstdint>

typedef _Float16 f16_t;
typedef __attribute__((ext_vector_type(8))) _Float16 f16x8;
typedef __attribute__((ext_vector_type(4))) _Float16 f16x4;
typedef __attribute__((ext_vector_type(4))) float f32x4;

#define HP      160      // padded H (150 -> 160): h/c row stride, U K-dim
#define NCOL    640      // 160 j x 4 gates (P is [v][j][g] interleaved)
#define KXP     320      // padded X_SIZE (300 -> 320)
#define NNODES  524287
#define LEAF_S  262143
#define LEAF_M  262144
#define NVOCAB  50000
#define AST     168      // A_sh stride (f16): 16B-aligned, 2-way-bank-free

__device__ __forceinline__ float frcp(float x) { return __builtin_amdgcn_rcpf(x); }
__device__ __forceinline__ float sigf(float x) { return frcp(1.0f + __expf(-x)); }
__device__ __forceinline__ float tanhf_(float x) {
  return 1.0f - 2.0f * frcp(1.0f + __expf(2.0f * x));
}
__device__ __forceinline__ f16x8 zero8() {
  f16x8 z;
#pragma unroll
  for (int i = 0; i < 8; ++i) z[i] = (_Float16)0.0f;
  return z;
}
__device__ __forceinline__ f32x4 zero4() {
  f32x4 z;
#pragma unroll
  for (int i = 0; i < 4; ++i) z[i] = 0.0f;
  return z;
}

// WreT[colIdx][k], colIdx = j*4+g (interleaved, matches P);
// UreT[col][k], col = g*160+j (g-major, matches B staging); bre interleaved.
__global__ void prep_params(const float* __restrict__ W_iou, const float* __restrict__ U_iou,
                            const float* __restrict__ b_iou, const float* __restrict__ W_f,
                            const float* __restrict__ U_f, const float* __restrict__ b_f,
                            f16_t* __restrict__ WreT, f16_t* __restrict__ UreT,
                            float* __restrict__ bre) {
  int idx = blockIdx.x * 256 + threadIdx.x;
  if (idx < NCOL * KXP) {
    int col = idx / KXP, k = idx % KXP;
    int j = col >> 2, g = col & 3;
    float v = 0.0f;
    if (k < 300 && j < 150) v = (g < 3) ? W_iou[k * 450 + g * 150 + j] : W_f[k * 150 + j];
    WreT[idx] = (f16_t)v;
  } else if (idx < NCOL * KXP + NCOL * HP) {
    int i2 = idx - NCOL * KXP;
    int col = i2 / HP, k = i2 % HP;
    int g = col / 160, j = col % 160;
    float v = 0.0f;
    if (k < 150 && j < 150) v = (g < 3) ? U_iou[k * 450 + g * 150 + j] : U_f[k * 150 + j];
    UreT[i2] = (f16_t)v;
  } else if (idx < NCOL * KXP + NCOL * HP + NCOL) {
    int col = idx - (NCOL * KXP + NCOL * HP);
    int j = col >> 2, g = col & 3;
    bre[col] = (j < 150) ? ((g < 3) ? b_iou[g * 150 + j] : b_f[j]) : 0.0f;
  }
}

// P[v][j][g] = emb @ W + b, fp16, 50000 x 640 (interleaved cols).
__global__ __launch_bounds__(256) void gemm_p(const float* __restrict__ emb,
                                              const f16_t* __restrict__ WreT,
                                              const float* __restrict__ bre,
                                              f16_t* __restrict__ P) {
  __shared__ __align__(16) f16_t A_sh[64 * 328];
  __shared__ __align__(16) f16_t B_sh[128 * 40];
  const int tid = threadIdx.x;
  const int wid = tid >> 6, lane = tid & 63, l15 = lane & 15, q = lane >> 4;
  const int row0 = blockIdx.x * 64;

#pragma unroll
  for (int i = 0; i < 10; ++i) {
    int ch = tid + 256 * i;
    int r = ch / 40, kc = (ch % 40) * 8;
    int grow = row0 + r;
    f16x8 hv;
    if (grow < NVOCAB && kc + 8 <= 300) {
      float4 a = *(const float4*)&emb[grow * 300 + kc];
      float4 b = *(const float4*)&emb[grow * 300 + kc + 4];
      hv[0] = (_Float16)a.x; hv[1] = (_Float16)a.y; hv[2] = (_Float16)a.z; hv[3] = (_Float16)a.w;
      hv[4] = (_Float16)b.x; hv[5] = (_Float16)b.y; hv[6] = (_Float16)b.z; hv[7] = (_Float16)b.w;
    } else {
#pragma unroll
      for (int e = 0; e < 8; ++e) {
        int k = kc + e;
        float v = (grow < NVOCAB && k < 300) ? emb[grow * 300 + k] : 0.0f;
        hv[e] = (_Float16)v;
      }
    }
    *(f16x8*)&A_sh[r * 328 + kc] = hv;
  }
  __syncthreads();

  for (int bn = 0; bn < 5; ++bn) {
    const int col0 = bn * 128;
    f32x4 acc[8];
#pragma unroll
    for (int t = 0; t < 8; ++t) acc[t] = zero4();
    for (int kk = 0; kk < KXP; kk += 32) {
#pragma unroll
      for (int i = 0; i < 2; ++i) {
        int ch = tid + 256 * i;
        int cidx = ch >> 2, kc = (ch & 3) * 8;
        *(f16x8*)&B_sh[cidx * 40 + kc] =
            *(const f16x8*)&WreT[(col0 + cidx) * KXP + kk + kc];
      }
      __syncthreads();
      f16x8 af = *(const f16x8*)&A_sh[(16 * wid + l15) * 328 + kk + q * 8];
#pragma unroll
      for (int t = 0; t < 8; ++t) {
        f16x8 bfr = *(const f16x8*)&B_sh[(t * 16 + l15) * 40 + q * 8];
        acc[t] = __builtin_amdgcn_mfma_f32_16x16x32_f16(af, bfr, acc[t], 0, 0, 0);
      }
      __syncthreads();
    }
#pragma unroll
    for (int t = 0; t < 8; ++t) {
      int col = col0 + t * 16 + l15;
      float bias = bre[col];
#pragma unroll
      for (int r2 = 0; r2 < 4; ++r2) {
        int row = row0 + 16 * wid + q * 4 + r2;
        if (row < NVOCAB) P[(long)row * NCOL + col] = (f16_t)(acc[t][r2] + bias);
      }
    }
  }
}

// Vocab-space leaf h/c tables: Hleaf[v][j], Cleaf[v][j] (f16).
__global__ void leafhc_kernel(const f16_t* __restrict__ P, f16_t* __restrict__ Hleaf,
                              f16_t* __restrict__ Cleaf) {
  int idx = blockIdx.x * 256 + threadIdx.x;
  if (idx >= NVOCAB * 80) return;
  int v = idx / 80, t = idx % 80;
  f16x8 pk = *(const f16x8*)&P[(long)v * NCOL + t * 8];
#pragma unroll
  for (int e = 0; e < 2; ++e) {
    float iv = (float)pk[e * 4 + 0], ov = (float)pk[e * 4 + 1], uv = (float)pk[e * 4 + 2];
    float cl = sigf(iv) * tanhf_(uv);
    float hl = sigf(ov) * tanhf_(cl);
    Hleaf[(long)v * HP + t * 2 + e] = (f16_t)hl;   // pads (t>=75) stay exactly 0
    Cleaf[(long)v * HP + t * 2 + e] = (f16_t)cl;
  }
}

// Oleaf[v] = Hleaf[v] @ W_out + b_out (row stride 8 floats for alignment).
__global__ void oleaf_kernel(const f16_t* __restrict__ Hleaf, const float* __restrict__ W_out,
                             const float* __restrict__ b_out, float* __restrict__ Oleaf) {
  const int tid = threadIdx.x;
  const int row = blockIdx.x * 16 + (tid >> 4), l = tid & 15;
  if (row >= NVOCAB) return;
  float acc[5] = {0, 0, 0, 0, 0};
  for (int j = l; j < 150; j += 16) {
    float hv = (float)Hleaf[(long)row * HP + j];
#pragma unroll
    for (int m = 0; m < 5; ++m) acc[m] += hv * W_out[j * 5 + m];
  }
#pragma unroll
  for (int m = 0; m < 5; ++m) {
    float vv = acc[m];
    vv += __shfl_xor(vv, 1);
    vv += __shfl_xor(vv, 2);
    vv += __shfl_xor(vv, 4);
    vv += __shfl_xor(vv, 8);
    if (l == 0) Oleaf[(long)row * 8 + m] = vv + b_out[m];
  }
}

// Leaf output rows: pure 20B gather from Oleaf.
__global__ void leafout_kernel(const int* __restrict__ x_id, const float* __restrict__ Oleaf,
                               float* __restrict__ out) {
  int leaf = blockIdx.x * 256 + threadIdx.x;
  int xv = x_id[LEAF_S + leaf];
  const float* O = Oleaf + (long)xv * 8;
  float4 o4 = *(const float4*)O;
  float o5 = O[4];
  long base = ((long)LEAF_S + leaf) * 5;
  out[base + 0] = o4.x; out[base + 1] = o4.y; out[base + 2] = o4.z;
  out[base + 3] = o4.w; out[base + 4] = o5;
}

// Single-level kernel for LEVEL 17 ONLY: 262144 leaves -> 131072 parents.
__global__ __launch_bounds__(256, 3) void level17_kernel(
    const int* __restrict__ x_id, const f16_t* __restrict__ P,
    const f16_t* __restrict__ UreT, const f16_t* __restrict__ Hleaf,
    const f16_t* __restrict__ Cleaf, f16_t* __restrict__ Hout,
    f16_t* __restrict__ Cout, const float* __restrict__ W_out,
    const float* __restrict__ b_out, float* __restrict__ out) {
  __shared__ __align__(16) f16_t A_sh[64 * AST];
  __shared__ __align__(16) f16_t B_sh[128 * 40];
  const int tid = threadIdx.x;
  const int wid = tid >> 6, lane = tid & 63, l15 = lane & 15, q = lane >> 4;
  const int p0 = blockIdx.x * 32;
  const int s1 = (1 << 17) - 1;                  // 131071
  const long childbase = 2L * s1 + 1 + 2 * p0;   // first child (leaf) node id

#pragma unroll
  for (int i = 0; i < 5; ++i) {
    int ch = tid + 256 * i;
    int r = ch / 20, kc = (ch % 20) * 8;
    int xv = x_id[childbase + r];
    *(f16x8*)&A_sh[r * AST + kc] = *(const f16x8*)&Hleaf[(long)xv * HP + kc];
  }
  __syncthreads();

  int xvp[2], xvl[2], xvr[2];
#pragma unroll
  for (int rr = 0; rr < 2; ++rr) {
    int pl = 8 * wid + 2 * q + rr;
    xvp[rr] = x_id[(long)s1 + p0 + pl];
    xvl[rr] = x_id[childbase + 2 * pl];
    xvr[rr] = x_id[childbase + 2 * pl + 1];
  }
  float oacc[2][5] = {};

  for (int jt = 0; jt < 5; ++jt) {
    const int j0 = jt * 32;
    f32x4 acc[4][2];
#pragma unroll
    for (int g = 0; g < 4; ++g)
#pragma unroll
      for (int jh = 0; jh < 2; ++jh) acc[g][jh] = zero4();

    for (int kk = 0; kk < HP; kk += 32) {
#pragma unroll
      for (int i = 0; i < 2; ++i) {
        int ch = tid + 256 * i;
        int cidx = ch >> 2, kc = (ch & 3) * 8;
        int g = cidx >> 5, jj = cidx & 31;
        int col = g * HP + j0 + jj;
        *(f16x8*)&B_sh[cidx * 40 + kc] = *(const f16x8*)&UreT[col * HP + kk + kc];
      }
      __syncthreads();
      f16x8 af = *(const f16x8*)&A_sh[(16 * wid + l15) * AST + kk + q * 8];
#pragma unroll
      for (int g = 0; g < 4; ++g)
#pragma unroll
        for (int jh = 0; jh < 2; ++jh) {
          f16x8 bfr = *(const f16x8*)&B_sh[(g * 32 + jh * 16 + l15) * 40 + q * 8];
          acc[g][jh] = __builtin_amdgcn_mfma_f32_16x16x32_f16(af, bfr, acc[g][jh], 0, 0, 0);
        }
      __syncthreads();
    }

#pragma unroll
    for (int rr = 0; rr < 2; ++rr) {
      const int r = rr * 2;
      const int pl = 8 * wid + 2 * q + rr;      // local parent 0..31
      const f16_t* Prp = P + (long)xvp[rr] * NCOL;
#pragma unroll
      for (int jh = 0; jh < 2; ++jh) {
        const int j = j0 + jh * 16 + l15;
        f16x4 pp = *(const f16x4*)&Prp[j * 4];
        float ipre = (float)pp[0] + acc[0][jh][r] + acc[0][jh][r + 1];
        float opre = (float)pp[1] + acc[1][jh][r] + acc[1][jh][r + 1];
        float upre = (float)pp[2] + acc[2][jh][r] + acc[2][jh][r + 1];
        float pf   = (float)pp[3];
        float fl = sigf(pf + acc[3][jh][r]);
        float fr = sigf(pf + acc[3][jh][r + 1]);
        float clv = (float)Cleaf[(long)xvl[rr] * HP + j];
        float crv = (float)Cleaf[(long)xvr[rr] * HP + j];
        float cn = sigf(ipre) * tanhf_(upre) + fl * clv + fr * crv;
        float hn = sigf(opre) * tanhf_(cn);
        Hout[(long)(p0 + pl) * HP + j] = (f16_t)hn;   // pads stay exactly 0
        Cout[(long)(p0 + pl) * HP + j] = (f16_t)cn;
        int wbase = (j < 150) ? j * 5 : 0;            // hn==0 on pads
#pragma unroll
        for (int m = 0; m < 5; ++m) oacc[rr][m] += hn * W_out[wbase + m];
      }
    }
  }

#pragma unroll
  for (int rr = 0; rr < 2; ++rr) {
    int pl = 8 * wid + 2 * q + rr;
#pragma unroll
    for (int m = 0; m < 5; ++m) {
      float v = oacc[rr][m];
      v += __shfl_xor(v, 1);
      v += __shfl_xor(v, 2);
      v += __shfl_xor(v, 4);
      v += __shfl_xor(v, 8);
      if (l15 == 0) out[((long)s1 + p0 + pl) * 5 + m] = v + b_out[m];
    }
  }
}

// Two fused levels per block (round-0 proven structure).
template <bool LEAF>
__global__ __launch_bounds__(256, 3) void fused_kernel(
    const int* __restrict__ x_id, const f16_t* __restrict__ P,
    const f16_t* __restrict__ UreT, const f16_t* __restrict__ Hc,
    const f16_t* __restrict__ Cc, f16_t* __restrict__ Hout,
    f16_t* __restrict__ Cout, const float* __restrict__ W_out,
    const float* __restrict__ b_out, float* __restrict__ out, int s1, int M1) {
  __shared__ __align__(16) f16_t A_sh[64 * AST];
  __shared__ __align__(16) f16_t A2_sh[32 * AST];
  __shared__ __align__(16) f16_t B_sh[128 * 40];
  __shared__ f16_t C_sh[32 * 160];
  const int tid = threadIdx.x;
  const int wid = tid >> 6, lane = tid & 63, l15 = lane & 15, q = lane >> 4;
  const int p0 = blockIdx.x * 32;
  const long childbase = 2L * s1 + 1 + 2 * p0;

#pragma unroll
  for (int i = 0; i < 5; ++i) {
    int ch = tid + 256 * i;
    int r = ch / 20, kc = (ch % 20) * 8;
    f16x8 v;
    if (LEAF) {
      int xv = x_id[childbase + r];
      v = *(const f16x8*)&Hc[(long)xv * HP + kc];
    } else {
      v = *(const f16x8*)&Hc[(long)(2 * p0 + r) * HP + kc];
    }
    *(f16x8*)&A_sh[r * AST + kc] = v;
  }
  __syncthreads();

  int xvp[2], xvl[2], xvr[2];
#pragma unroll
  for (int rr = 0; rr < 2; ++rr) {
    int pl = 8 * wid + 2 * q + rr;
    long pn = (long)s1 + p0 + pl;
    xvp[rr] = x_id[pn];
    if (LEAF) {
      xvl[rr] = x_id[childbase + 2 * pl];
      xvr[rr] = x_id[childbase + 2 * pl + 1];
    }
  }
  float oacc1[2][5] = {};

  for (int jt = 0; jt < 5; ++jt) {
    const int j0 = jt * 32;
    f32x4 acc[4][2];
#pragma unroll
    for (int g = 0; g < 4; ++g)
#pragma unroll
      for (int jh = 0; jh < 2; ++jh) acc[g][jh] = zero4();

    for (int kk = 0; kk < HP; kk += 32) {
#pragma unroll
      for (int i = 0; i < 2; ++i) {
        int ch = tid + 256 * i;
        int cidx = ch >> 2, kc = (ch & 3) * 8;
        int g = cidx >> 5, jj = cidx & 31;
        int col = g * HP + j0 + jj;
        *(f16x8*)&B_sh[cidx * 40 + kc] = *(const f16x8*)&UreT[col * HP + kk + kc];
      }
      __syncthreads();
      f16x8 af = *(const f16x8*)&A_sh[(16 * wid + l15) * AST + kk + q * 8];
#pragma unroll
      for (int g = 0; g < 4; ++g)
#pragma unroll
        for (int jh = 0; jh < 2; ++jh) {
          f16x8 bfr = *(const f16x8*)&B_sh[(g * 32 + jh * 16 + l15) * 40 + q * 8];
          acc[g][jh] = __builtin_amdgcn_mfma_f32_16x16x32_f16(af, bfr, acc[g][jh], 0, 0, 0);
        }
      __syncthreads();
    }

#pragma unroll
    for (int rr = 0; rr < 2; ++rr) {
      const int r = rr * 2;
      const int lr0 = 16 * wid + q * 4 + r;
      const int pl = lr0 >> 1;
      const f16_t* Prp = P + (long)xvp[rr] * NCOL;
#pragma unroll
      for (int jh = 0; jh < 2; ++jh) {
        const int j = j0 + jh * 16 + l15;
        f16x4 pp = *(const f16x4*)&Prp[j * 4];
        float ipre = (float)pp[0] + acc[0][jh][r] + acc[0][jh][r + 1];
        float opre = (float)pp[1] + acc[1][jh][r] + acc[1][jh][r + 1];
        float upre = (float)pp[2] + acc[2][jh][r] + acc[2][jh][r + 1];
        float pf   = (float)pp[3];
        float fl = sigf(pf + acc[3][jh][r]);
        float fr = sigf(pf + acc[3][jh][r + 1]);
        float clv, crv;
        if (LEAF) {
          clv = (float)Cc[(long)xvl[rr] * HP + j];
          crv = (float)Cc[(long)xvr[rr] * HP + j];
        } else {
          clv = (float)Cc[(long)(2 * p0 + lr0) * HP + j];
          crv = (float)Cc[(long)(2 * p0 + lr0 + 1) * HP + j];
        }
        float cn = sigf(ipre) * tanhf_(upre) + fl * clv + fr * crv;
        float hn = sigf(opre) * tanhf_(cn);
        A2_sh[pl * AST + j] = (f16_t)hn;
        C_sh[pl * 160 + j] = (f16_t)cn;
        int wbase = (j < 150) ? j * 5 : 0;
#pragma unroll
        for (int m = 0; m < 5; ++m) oacc1[rr][m] += hn * W_out[wbase + m];
      }
    }
  }

#pragma unroll
  for (int rr = 0; rr < 2; ++rr) {
    int pl = 8 * wid + 2 * q + rr;
#pragma unroll
    for (int m = 0; m < 5; ++m) {
      float v = oacc1[rr][m];
      v += __shfl_xor(v, 1);
      v += __shfl_xor(v, 2);
      v += __shfl_xor(v, 4);
      v += __shfl_xor(v, 8);
      if (l15 == 0) out[((long)s1 + p0 + pl) * 5 + m] = v + b_out[m];
    }
  }

  const int s2 = (s1 - 1) >> 1;
  const int p02 = p0 >> 1;
  const bool act2 = (wid < 2);
  int xvp2[2];
#pragma unroll
  for (int rr = 0; rr < 2; ++rr) {
    int pl = 8 * wid + 2 * q + rr;
    long pn = (long)s2 + p02 + (act2 ? pl : 0);
    xvp2[rr] = x_id[pn];
  }
  float oacc2[2][5] = {};

  for (int jt = 0; jt < 5; ++jt) {
    const int j0 = jt * 32;
    f32x4 acc[4][2];
#pragma unroll
    for (int g = 0; g < 4; ++g)
#pragma unroll
      for (int jh = 0; jh < 2; ++jh) acc[g][jh] = zero4();

    for (int kk = 0; kk < HP; kk += 32) {
#pragma unroll
      for (int i = 0; i < 2; ++i) {
        int ch = tid + 256 * i;
        int cidx = ch >> 2, kc = (ch & 3) * 8;
        int g = cidx >> 5, jj = cidx & 31;
        int col = g * HP + j0 + jj;
        *(f16x8*)&B_sh[cidx * 40 + kc] = *(const f16x8*)&UreT[col * HP + kk + kc];
      }
      __syncthreads();
      if (act2) {
        f16x8 af = *(const f16x8*)&A2_sh[(16 * wid + l15) * AST + kk + q * 8];
#pragma unroll
        for (int g = 0; g < 4; ++g)
#pragma unroll
          for (int jh = 0; jh < 2; ++jh) {
            f16x8 bfr = *(const f16x8*)&B_sh[(g * 32 + jh * 16 + l15) * 40 + q * 8];
            acc[g][jh] = __builtin_amdgcn_mfma_f32_16x16x32_f16(af, bfr, acc[g][jh], 0, 0, 0);
          }
      }
      __syncthreads();
    }

    if (act2) {
#pragma unroll
      for (int rr = 0; rr < 2; ++rr) {
        const int r = rr * 2;
        const int lr0 = 16 * wid + q * 4 + r;
        const int pl = lr0 >> 1;
        const f16_t* Prp = P + (long)xvp2[rr] * NCOL;
#pragma unroll
        for (int jh = 0; jh < 2; ++jh) {
          const int j = j0 + jh * 16 + l15;
          f16x4 pp = *(const f16x4*)&Prp[j * 4];
          float ipre = (float)pp[0] + acc[0][jh][r] + acc[0][jh][r + 1];
          float opre = (float)pp[1] + acc[1][jh][r] + acc[1][jh][r + 1];
          float upre = (float)pp[2] + acc[2][jh][r] + acc[2][jh][r + 1];
          float pf   = (float)pp[3];
          float fl = sigf(pf + acc[3][jh][r]);
          float fr = sigf(pf + acc[3][jh][r + 1]);
          float clv = (float)C_sh[lr0 * 160 + j];
          float crv = (float)C_sh[(lr0 + 1) * 160 + j];
          float cn = sigf(ipre) * tanhf_(upre) + fl * clv + fr * crv;
          float hn = sigf(opre) * tanhf_(cn);
          Hout[(long)(p02 + pl) * HP + j] = (f16_t)hn;
          Cout[(long)(p02 + pl) * HP + j] = (f16_t)cn;
          int wbase = (j < 150) ? j * 5 : 0;
#pragma unroll
          for (int m = 0; m < 5; ++m) oacc2[rr][m] += hn * W_out[wbase + m];
        }
      }
    }
  }

  if (act2) {
#pragma unroll
    for (int rr = 0; rr < 2; ++rr) {
      int pl = 8 * wid + 2 * q + rr;
#pragma unroll
      for (int m = 0; m < 5; ++m) {
        float v = oacc2[rr][m];
        v += __shfl_xor(v, 1);
        v += __shfl_xor(v, 2);
        v += __shfl_xor(v, 4);
        v += __shfl_xor(v, 8);
        if (l15 == 0) out[((long)s2 + p02 + pl) * 5 + m] = v + b_out[m];
      }
    }
  }
}

// VALU-direct kernel for SMALL levels (M <= 4096): one block per parent,
// lane j owns output column j. U columns are contiguous 320-B streams in
// UreT[col][k]; hl/hr staged once in LDS (640 B) and read as wave-uniform
// broadcasts. Serial critical path ~19-iter k-loop (~1-2 us) vs the ~50 us
// barrier-phased MFMA structure — these levels are pure latency.
__global__ __launch_bounds__(256) void small_level(
    const int* __restrict__ x_id, const f16_t* __restrict__ P,
    const f16_t* __restrict__ UreT, const f16_t* __restrict__ Hc,
    const f16_t* __restrict__ Cc, f16_t* __restrict__ Hp, f16_t* __restrict__ Cp,
    const float* __restrict__ W_out, const float* __restrict__ b_out,
    float* __restrict__ out, int s) {
  __shared__ __align__(16) f16_t hlr[320];     // [0..159]=hl, [160..319]=hr
  __shared__ float partial[4][5];
  const int tid = threadIdx.x;
  const int p = blockIdx.x;
  const long cb = (long)(2 * p) * HP;          // rows 2p,2p+1 are contiguous

  if (tid < 40) *(f16x8*)&hlr[tid * 8] = *(const f16x8*)&Hc[cb + tid * 8];
  __syncthreads();

  const int j = tid;                           // 0..159 active
  float ai = 0.f, ao = 0.f, au = 0.f, afl = 0.f, afr = 0.f;
  float hn = 0.f;
  float contrib[5] = {0.f, 0.f, 0.f, 0.f, 0.f};
  if (j < HP) {
    const f16_t* Ui = &UreT[(long)(0 * HP + j) * HP];
    const f16_t* Uo = &UreT[(long)(1 * HP + j) * HP];
    const f16_t* Uu = &UreT[(long)(2 * HP + j) * HP];
    const f16_t* Uf = &UreT[(long)(3 * HP + j) * HP];
#pragma unroll 5
    for (int k8 = 0; k8 < 19; ++k8) {          // k < 152 (150 real; pads = 0)
      f16x8 hl8 = *(const f16x8*)&hlr[k8 * 8];
      f16x8 hr8 = *(const f16x8*)&hlr[160 + k8 * 8];
      f16x8 ui8 = *(const f16x8*)&Ui[k8 * 8];
      f16x8 uo8 = *(const f16x8*)&Uo[k8 * 8];
      f16x8 uu8 = *(const f16x8*)&Uu[k8 * 8];
      f16x8 uf8 = *(const f16x8*)&Uf[k8 * 8];
#pragma unroll
      for (int e = 0; e < 8; ++e) {
        float hlv = (float)hl8[e], hrv = (float)hr8[e];
        float hsv = hlv + hrv;
        ai  += hsv * (float)ui8[e];
        ao  += hsv * (float)uo8[e];
        au  += hsv * (float)uu8[e];
        afl += hlv * (float)uf8[e];
        afr += hrv * (float)uf8[e];
      }
    }
    int xv = x_id[(long)s + p];
    f16x4 pp = *(const f16x4*)&P[(long)xv * NCOL + j * 4];
    float ipre = (float)pp[0] + ai;
    float opre = (float)pp[1] + ao;
    float upre = (float)pp[2] + au;
    float pf   = (float)pp[3];
    float fl = sigf(pf + afl), fr = sigf(pf + afr);
    float clv = (float)Cc[cb + j];
    float crv = (float)Cc[cb + HP + j];
    float cn = sigf(ipre) * tanhf_(upre) + fl * clv + fr * crv;
    hn = sigf(opre) * tanhf_(cn);
    Hp[(long)p * HP + j] = (f16_t)hn;          // pads compute to exactly 0
    Cp[(long)p * HP + j] = (f16_t)cn;
    int wbase = (j < 150) ? j * 5 : 0;         // hn==0 on pads
#pragma unroll
    for (int m = 0; m < 5; ++m) contrib[m] = hn * W_out[wbase + m];
  }
  const int w = tid >> 6, l = tid & 63;
#pragma unroll
  for (int m = 0; m < 5; ++m) {
    float v = contrib[m];
    v += __shfl_xor(v, 1);  v += __shfl_xor(v, 2);  v += __shfl_xor(v, 4);
    v += __shfl_xor(v, 8);  v += __shfl_xor(v, 16); v += __shfl_xor(v, 32);
    if (l == 0) partial[w][m] = v;
  }
  __syncthreads();
  if (tid < 5) {
    float v = partial[0][tid] + partial[1][tid] + partial[2][tid] + partial[3][tid];
    out[((long)s + p) * 5 + tid] = v + b_out[tid];
  }
}

extern "C" void kernel_launch(void* const* d_in, const int* in_sizes, int n_in,
                              void* d_out, int out_size, void* d_ws, size_t ws_size,
                              hipStream_t stream) {
  const int* x_id   = (const int*)d_in[0];
  const float* emb  = (const float*)d_in[1];
  const float* W_iou = (const float*)d_in[2];
  const float* U_iou = (const float*)d_in[3];
  const float* b_iou = (const float*)d_in[4];
  const float* W_f   = (const float*)d_in[5];
  const float* U_f   = (const float*)d_in[6];
  const float* b_f   = (const float*)d_in[7];
  const float* W_out = (const float*)d_in[8];
  const float* b_out = (const float*)d_in[9];
  float* out = (float*)d_out;
  char* ws = (char*)d_ws;

  // workspace carve (bytes), peak 180,503,040 <= 182,103,040 budget.
  // All region reuses are stream-ordered (writer launched after last reader).
  f16_t* WreT  = (f16_t*)(ws + 0);              // 409,600
  f16_t* UreT  = (f16_t*)(ws + 409600);         // 204,800
  float* bre   = (float*)(ws + 614400);         // 2,560
  f16_t* P     = (f16_t*)(ws + 616960);         // 64,000,000 (persistent)
  f16_t* Hleaf = (f16_t*)(ws + 64616960);       // 16,000,000 (dead after L17)
  f16_t* Cleaf = (f16_t*)(ws + 80616960);       // 16,000,000 (dead after L17)
  float* Oleaf = (float*)(ws + 96616960);       // 1,600,000 (dead after leafout)
  f16_t* H17   = (f16_t*)(ws + 96616960);       // 41,943,040 (131072 rows)
  f16_t* C17   = (f16_t*)(ws + 138560000);      // 41,943,040 -> ends 180,503,040
  f16_t* H15 = (f16_t*)(ws + 64616960);         // 10,485,760 (32768 rows) over Hleaf
  f16_t* C15 = (f16_t*)(ws + 75102720);         // 10,485,760 -> ends 85,588,480
  f16_t* H13 = (f16_t*)(ws + 96616960);         //  2,621,440 (8192 rows) over H17
  f16_t* C13 = (f16_t*)(ws + 99238400);         //  2,621,440
  // VALU-level buffers: 85,588,480 .. 90,830,720 (after H15/C15, before 96.6M).
  // First written after fused(14,13) completes — stream-ordered vs H15/C15 reads.
  char* vb = ws + 85588480;
  f16_t* VH[13]; f16_t* VC[13];
  for (int L = 12; L >= 0; --L) {
    size_t rows = (size_t)1 << L;
    VH[L] = (f16_t*)vb; vb += rows * 320;
    VC[L] = (f16_t*)vb; vb += rows * 320;
  }

  prep_params<<<1203, 256, 0, stream>>>(W_iou, U_iou, b_iou, W_f, U_f, b_f, WreT, UreT, bre);
  gemm_p<<<782, 256, 0, stream>>>(emb, WreT, bre, P);
  leafhc_kernel<<<15625, 256, 0, stream>>>(P, Hleaf, Cleaf);
  oleaf_kernel<<<3125, 256, 0, stream>>>(Hleaf, W_out, b_out, Oleaf);
  leafout_kernel<<<1024, 256, 0, stream>>>(x_id, Oleaf, out);

  // level 17 standalone (slim LDS): leaves -> H17/C17
  level17_kernel<<<4096, 256, 0, stream>>>(x_id, P, UreT, Hleaf, Cleaf, H17, C17,
                                           W_out, b_out, out);
  // fused pairs for the big levels:
  fused_kernel<false><<<2048, 256, 0, stream>>>(x_id, P, UreT, H17, C17, H15, C15,
                                                W_out, b_out, out, (1 << 16) - 1, 1 << 16);
  fused_kernel<false><<<512, 256, 0, stream>>>(x_id, P, UreT, H15, C15, H13, C13,
                                               W_out, b_out, out, (1 << 14) - 1, 1 << 14);
  // VALU-direct small levels 12..0 (one block per parent):
  small_level<<<4096, 256, 0, stream>>>(x_id, P, UreT, H13, C13, VH[12], VC[12],
                                        W_out, b_out, out, (1 << 12) - 1);
  for (int L = 11; L >= 0; --L) {
    small_level<<<(1 << L), 256, 0, stream>>>(x_id, P, UreT, VH[L + 1], VC[L + 1],
                                              VH[L], VC[L], W_out, b_out, out,
                                              (1 << L) - 1);
  }

  (void)in_sizes; (void)n_in; (void)out_size; (void)ws_size;
}

// Round 6
// 950.089 us; speedup vs baseline: 1.0434x; 1.0434x over previous
//
#include <hip/hip_runtime.h>
#include <cstdint>

typedef _Float16 f16_t;
typedef __attribute__((ext_vector_type(8))) _Float16 f16x8;
typedef __attribute__((ext_vector_type(4))) _Float16 f16x4;
typedef __attribute__((ext_vector_type(2))) _Float16 f16x2;
typedef __attribute__((ext_vector_type(4))) float f32x4;

#define HP      160      // padded H (150 -> 160): h/c row stride, U K-dim
#define NCOL    640      // 160 j x 4 gates (P is [v][j][g] interleaved)
#define KXP     320      // padded X_SIZE (300 -> 320)
#define NNODES  524287
#define LEAF_S  262143
#define LEAF_M  262144
#define NVOCAB  50000
#define AST     168      // A_sh stride (f16): 16B-aligned, 2-way-bank-free
#define PPB     4        // parents per block in small_level

__device__ __forceinline__ float frcp(float x) { return __builtin_amdgcn_rcpf(x); }
__device__ __forceinline__ float sigf(float x) { return frcp(1.0f + __expf(-x)); }
__device__ __forceinline__ float tanhf_(float x) {
  return 1.0f - 2.0f * frcp(1.0f + __expf(2.0f * x));
}
__device__ __forceinline__ f16x8 zero8() {
  f16x8 z;
#pragma unroll
  for (int i = 0; i < 8; ++i) z[i] = (_Float16)0.0f;
  return z;
}
__device__ __forceinline__ f32x4 zero4() {
  f32x4 z;
#pragma unroll
  for (int i = 0; i < 4; ++i) z[i] = 0.0f;
  return z;
}

// WreT[colIdx][k], colIdx = j*4+g (interleaved, matches P);
// UreT[col][k], col = g*160+j (g-major, matches B staging); bre interleaved.
// UP2[(k2*160+j)*8 + (k&1)*4 + g]: coalesced-by-j layout for small_level
// (lane j loads 16 B contiguous per k-pair).
__global__ void prep_params(const float* __restrict__ W_iou, const float* __restrict__ U_iou,
                            const float* __restrict__ b_iou, const float* __restrict__ W_f,
                            const float* __restrict__ U_f, const float* __restrict__ b_f,
                            f16_t* __restrict__ WreT, f16_t* __restrict__ UreT,
                            float* __restrict__ bre, f16_t* __restrict__ UP2) {
  int idx = blockIdx.x * 256 + threadIdx.x;
  if (idx < NCOL * KXP) {
    int col = idx / KXP, k = idx % KXP;
    int j = col >> 2, g = col & 3;
    float v = 0.0f;
    if (k < 300 && j < 150) v = (g < 3) ? W_iou[k * 450 + g * 150 + j] : W_f[k * 150 + j];
    WreT[idx] = (f16_t)v;
  } else if (idx < NCOL * KXP + NCOL * HP) {
    int i2 = idx - NCOL * KXP;
    int col = i2 / HP, k = i2 % HP;
    int g = col / 160, j = col % 160;
    float v = 0.0f;
    if (k < 150 && j < 150) v = (g < 3) ? U_iou[k * 450 + g * 150 + j] : U_f[k * 150 + j];
    UreT[i2] = (f16_t)v;
  } else if (idx < NCOL * KXP + NCOL * HP + NCOL) {
    int col = idx - (NCOL * KXP + NCOL * HP);
    int j = col >> 2, g = col & 3;
    bre[col] = (j < 150) ? ((g < 3) ? b_iou[g * 150 + j] : b_f[j]) : 0.0f;
  } else if (idx < NCOL * KXP + NCOL * HP + NCOL + NCOL * HP) {
    int i3 = idx - (NCOL * KXP + NCOL * HP + NCOL);
    int slot = i3 & 7, t = i3 >> 3;
    int j = t % 160, k2 = t / 160;
    int k = 2 * k2 + (slot >> 2), g = slot & 3;
    float v = 0.0f;
    if (k < 150 && j < 150) v = (g < 3) ? U_iou[k * 450 + g * 150 + j] : U_f[k * 150 + j];
    UP2[i3] = (f16_t)v;
  }
}

// P[v][j][g] = emb @ W + b, fp16, 50000 x 640 (interleaved cols).
__global__ __launch_bounds__(256) void gemm_p(const float* __restrict__ emb,
                                              const f16_t* __restrict__ WreT,
                                              const float* __restrict__ bre,
                                              f16_t* __restrict__ P) {
  __shared__ __align__(16) f16_t A_sh[64 * 328];
  __shared__ __align__(16) f16_t B_sh[128 * 40];
  const int tid = threadIdx.x;
  const int wid = tid >> 6, lane = tid & 63, l15 = lane & 15, q = lane >> 4;
  const int row0 = blockIdx.x * 64;

#pragma unroll
  for (int i = 0; i < 10; ++i) {
    int ch = tid + 256 * i;
    int r = ch / 40, kc = (ch % 40) * 8;
    int grow = row0 + r;
    f16x8 hv;
    if (grow < NVOCAB && kc + 8 <= 300) {
      float4 a = *(const float4*)&emb[grow * 300 + kc];
      float4 b = *(const float4*)&emb[grow * 300 + kc + 4];
      hv[0] = (_Float16)a.x; hv[1] = (_Float16)a.y; hv[2] = (_Float16)a.z; hv[3] = (_Float16)a.w;
      hv[4] = (_Float16)b.x; hv[5] = (_Float16)b.y; hv[6] = (_Float16)b.z; hv[7] = (_Float16)b.w;
    } else {
#pragma unroll
      for (int e = 0; e < 8; ++e) {
        int k = kc + e;
        float v = (grow < NVOCAB && k < 300) ? emb[grow * 300 + k] : 0.0f;
        hv[e] = (_Float16)v;
      }
    }
    *(f16x8*)&A_sh[r * 328 + kc] = hv;
  }
  __syncthreads();

  for (int bn = 0; bn < 5; ++bn) {
    const int col0 = bn * 128;
    f32x4 acc[8];
#pragma unroll
    for (int t = 0; t < 8; ++t) acc[t] = zero4();
    for (int kk = 0; kk < KXP; kk += 32) {
#pragma unroll
      for (int i = 0; i < 2; ++i) {
        int ch = tid + 256 * i;
        int cidx = ch >> 2, kc = (ch & 3) * 8;
        *(f16x8*)&B_sh[cidx * 40 + kc] =
            *(const f16x8*)&WreT[(col0 + cidx) * KXP + kk + kc];
      }
      __syncthreads();
      f16x8 af = *(const f16x8*)&A_sh[(16 * wid + l15) * 328 + kk + q * 8];
#pragma unroll
      for (int t = 0; t < 8; ++t) {
        f16x8 bfr = *(const f16x8*)&B_sh[(t * 16 + l15) * 40 + q * 8];
        acc[t] = __builtin_amdgcn_mfma_f32_16x16x32_f16(af, bfr, acc[t], 0, 0, 0);
      }
      __syncthreads();
    }
#pragma unroll
    for (int t = 0; t < 8; ++t) {
      int col = col0 + t * 16 + l15;
      float bias = bre[col];
#pragma unroll
      for (int r2 = 0; r2 < 4; ++r2) {
        int row = row0 + 16 * wid + q * 4 + r2;
        if (row < NVOCAB) P[(long)row * NCOL + col] = (f16_t)(acc[t][r2] + bias);
      }
    }
  }
}

// Vocab-space leaf h/c tables: Hleaf[v][j], Cleaf[v][j] (f16).
__global__ void leafhc_kernel(const f16_t* __restrict__ P, f16_t* __restrict__ Hleaf,
                              f16_t* __restrict__ Cleaf) {
  int idx = blockIdx.x * 256 + threadIdx.x;
  if (idx >= NVOCAB * 80) return;
  int v = idx / 80, t = idx % 80;
  f16x8 pk = *(const f16x8*)&P[(long)v * NCOL + t * 8];
#pragma unroll
  for (int e = 0; e < 2; ++e) {
    float iv = (float)pk[e * 4 + 0], ov = (float)pk[e * 4 + 1], uv = (float)pk[e * 4 + 2];
    float cl = sigf(iv) * tanhf_(uv);
    float hl = sigf(ov) * tanhf_(cl);
    Hleaf[(long)v * HP + t * 2 + e] = (f16_t)hl;   // pads (t>=75) stay exactly 0
    Cleaf[(long)v * HP + t * 2 + e] = (f16_t)cl;
  }
}

// Oleaf[v] = Hleaf[v] @ W_out + b_out (row stride 8 floats for alignment).
__global__ void oleaf_kernel(const f16_t* __restrict__ Hleaf, const float* __restrict__ W_out,
                             const float* __restrict__ b_out, float* __restrict__ Oleaf) {
  const int tid = threadIdx.x;
  const int row = blockIdx.x * 16 + (tid >> 4), l = tid & 15;
  if (row >= NVOCAB) return;
  float acc[5] = {0, 0, 0, 0, 0};
  for (int j = l; j < 150; j += 16) {
    float hv = (float)Hleaf[(long)row * HP + j];
#pragma unroll
    for (int m = 0; m < 5; ++m) acc[m] += hv * W_out[j * 5 + m];
  }
#pragma unroll
  for (int m = 0; m < 5; ++m) {
    float vv = acc[m];
    vv += __shfl_xor(vv, 1);
    vv += __shfl_xor(vv, 2);
    vv += __shfl_xor(vv, 4);
    vv += __shfl_xor(vv, 8);
    if (l == 0) Oleaf[(long)row * 8 + m] = vv + b_out[m];
  }
}

// Leaf output rows: pure 20B gather from Oleaf.
__global__ void leafout_kernel(const int* __restrict__ x_id, const float* __restrict__ Oleaf,
                               float* __restrict__ out) {
  int leaf = blockIdx.x * 256 + threadIdx.x;
  int xv = x_id[LEAF_S + leaf];
  const float* O = Oleaf + (long)xv * 8;
  float4 o4 = *(const float4*)O;
  float o5 = O[4];
  long base = ((long)LEAF_S + leaf) * 5;
  out[base + 0] = o4.x; out[base + 1] = o4.y; out[base + 2] = o4.z;
  out[base + 3] = o4.w; out[base + 4] = o5;
}

// Single-level kernel for LEVEL 17 ONLY: 262144 leaves -> 131072 parents.
__global__ __launch_bounds__(256, 3) void level17_kernel(
    const int* __restrict__ x_id, const f16_t* __restrict__ P,
    const f16_t* __restrict__ UreT, const f16_t* __restrict__ Hleaf,
    const f16_t* __restrict__ Cleaf, f16_t* __restrict__ Hout,
    f16_t* __restrict__ Cout, const float* __restrict__ W_out,
    const float* __restrict__ b_out, float* __restrict__ out) {
  __shared__ __align__(16) f16_t A_sh[64 * AST];
  __shared__ __align__(16) f16_t B_sh[128 * 40];
  const int tid = threadIdx.x;
  const int wid = tid >> 6, lane = tid & 63, l15 = lane & 15, q = lane >> 4;
  const int p0 = blockIdx.x * 32;
  const int s1 = (1 << 17) - 1;                  // 131071
  const long childbase = 2L * s1 + 1 + 2 * p0;   // first child (leaf) node id

#pragma unroll
  for (int i = 0; i < 5; ++i) {
    int ch = tid + 256 * i;
    int r = ch / 20, kc = (ch % 20) * 8;
    int xv = x_id[childbase + r];
    *(f16x8*)&A_sh[r * AST + kc] = *(const f16x8*)&Hleaf[(long)xv * HP + kc];
  }
  __syncthreads();

  int xvp[2], xvl[2], xvr[2];
#pragma unroll
  for (int rr = 0; rr < 2; ++rr) {
    int pl = 8 * wid + 2 * q + rr;
    xvp[rr] = x_id[(long)s1 + p0 + pl];
    xvl[rr] = x_id[childbase + 2 * pl];
    xvr[rr] = x_id[childbase + 2 * pl + 1];
  }
  float oacc[2][5] = {};

  for (int jt = 0; jt < 5; ++jt) {
    const int j0 = jt * 32;
    f32x4 acc[4][2];
#pragma unroll
    for (int g = 0; g < 4; ++g)
#pragma unroll
      for (int jh = 0; jh < 2; ++jh) acc[g][jh] = zero4();

    for (int kk = 0; kk < HP; kk += 32) {
#pragma unroll
      for (int i = 0; i < 2; ++i) {
        int ch = tid + 256 * i;
        int cidx = ch >> 2, kc = (ch & 3) * 8;
        int g = cidx >> 5, jj = cidx & 31;
        int col = g * HP + j0 + jj;
        *(f16x8*)&B_sh[cidx * 40 + kc] = *(const f16x8*)&UreT[col * HP + kk + kc];
      }
      __syncthreads();
      f16x8 af = *(const f16x8*)&A_sh[(16 * wid + l15) * AST + kk + q * 8];
#pragma unroll
      for (int g = 0; g < 4; ++g)
#pragma unroll
        for (int jh = 0; jh < 2; ++jh) {
          f16x8 bfr = *(const f16x8*)&B_sh[(g * 32 + jh * 16 + l15) * 40 + q * 8];
          acc[g][jh] = __builtin_amdgcn_mfma_f32_16x16x32_f16(af, bfr, acc[g][jh], 0, 0, 0);
        }
      __syncthreads();
    }

#pragma unroll
    for (int rr = 0; rr < 2; ++rr) {
      const int r = rr * 2;
      const int pl = 8 * wid + 2 * q + rr;      // local parent 0..31
      const f16_t* Prp = P + (long)xvp[rr] * NCOL;
#pragma unroll
      for (int jh = 0; jh < 2; ++jh) {
        const int j = j0 + jh * 16 + l15;
        f16x4 pp = *(const f16x4*)&Prp[j * 4];
        float ipre = (float)pp[0] + acc[0][jh][r] + acc[0][jh][r + 1];
        float opre = (float)pp[1] + acc[1][jh][r] + acc[1][jh][r + 1];
        float upre = (float)pp[2] + acc[2][jh][r] + acc[2][jh][r + 1];
        float pf   = (float)pp[3];
        float fl = sigf(pf + acc[3][jh][r]);
        float fr = sigf(pf + acc[3][jh][r + 1]);
        float clv = (float)Cleaf[(long)xvl[rr] * HP + j];
        float crv = (float)Cleaf[(long)xvr[rr] * HP + j];
        float cn = sigf(ipre) * tanhf_(upre) + fl * clv + fr * crv;
        float hn = sigf(opre) * tanhf_(cn);
        Hout[(long)(p0 + pl) * HP + j] = (f16_t)hn;   // pads stay exactly 0
        Cout[(long)(p0 + pl) * HP + j] = (f16_t)cn;
        int wbase = (j < 150) ? j * 5 : 0;            // hn==0 on pads
#pragma unroll
        for (int m = 0; m < 5; ++m) oacc[rr][m] += hn * W_out[wbase + m];
      }
    }
  }

#pragma unroll
  for (int rr = 0; rr < 2; ++rr) {
    int pl = 8 * wid + 2 * q + rr;
#pragma unroll
    for (int m = 0; m < 5; ++m) {
      float v = oacc[rr][m];
      v += __shfl_xor(v, 1);
      v += __shfl_xor(v, 2);
      v += __shfl_xor(v, 4);
      v += __shfl_xor(v, 8);
      if (l15 == 0) out[((long)s1 + p0 + pl) * 5 + m] = v + b_out[m];
    }
  }
}

// Two fused levels per block (round-0 proven structure).
template <bool LEAF>
__global__ __launch_bounds__(256, 3) void fused_kernel(
    const int* __restrict__ x_id, const f16_t* __restrict__ P,
    const f16_t* __restrict__ UreT, const f16_t* __restrict__ Hc,
    const f16_t* __restrict__ Cc, f16_t* __restrict__ Hout,
    f16_t* __restrict__ Cout, const float* __restrict__ W_out,
    const float* __restrict__ b_out, float* __restrict__ out, int s1, int M1) {
  __shared__ __align__(16) f16_t A_sh[64 * AST];
  __shared__ __align__(16) f16_t A2_sh[32 * AST];
  __shared__ __align__(16) f16_t B_sh[128 * 40];
  __shared__ f16_t C_sh[32 * 160];
  const int tid = threadIdx.x;
  const int wid = tid >> 6, lane = tid & 63, l15 = lane & 15, q = lane >> 4;
  const int p0 = blockIdx.x * 32;
  const long childbase = 2L * s1 + 1 + 2 * p0;

#pragma unroll
  for (int i = 0; i < 5; ++i) {
    int ch = tid + 256 * i;
    int r = ch / 20, kc = (ch % 20) * 8;
    f16x8 v;
    if (LEAF) {
      int xv = x_id[childbase + r];
      v = *(const f16x8*)&Hc[(long)xv * HP + kc];
    } else {
      v = *(const f16x8*)&Hc[(long)(2 * p0 + r) * HP + kc];
    }
    *(f16x8*)&A_sh[r * AST + kc] = v;
  }
  __syncthreads();

  int xvp[2], xvl[2], xvr[2];
#pragma unroll
  for (int rr = 0; rr < 2; ++rr) {
    int pl = 8 * wid + 2 * q + rr;
    long pn = (long)s1 + p0 + pl;
    xvp[rr] = x_id[pn];
    if (LEAF) {
      xvl[rr] = x_id[childbase + 2 * pl];
      xvr[rr] = x_id[childbase + 2 * pl + 1];
    }
  }
  float oacc1[2][5] = {};

  for (int jt = 0; jt < 5; ++jt) {
    const int j0 = jt * 32;
    f32x4 acc[4][2];
#pragma unroll
    for (int g = 0; g < 4; ++g)
#pragma unroll
      for (int jh = 0; jh < 2; ++jh) acc[g][jh] = zero4();

    for (int kk = 0; kk < HP; kk += 32) {
#pragma unroll
      for (int i = 0; i < 2; ++i) {
        int ch = tid + 256 * i;
        int cidx = ch >> 2, kc = (ch & 3) * 8;
        int g = cidx >> 5, jj = cidx & 31;
        int col = g * HP + j0 + jj;
        *(f16x8*)&B_sh[cidx * 40 + kc] = *(const f16x8*)&UreT[col * HP + kk + kc];
      }
      __syncthreads();
      f16x8 af = *(const f16x8*)&A_sh[(16 * wid + l15) * AST + kk + q * 8];
#pragma unroll
      for (int g = 0; g < 4; ++g)
#pragma unroll
        for (int jh = 0; jh < 2; ++jh) {
          f16x8 bfr = *(const f16x8*)&B_sh[(g * 32 + jh * 16 + l15) * 40 + q * 8];
          acc[g][jh] = __builtin_amdgcn_mfma_f32_16x16x32_f16(af, bfr, acc[g][jh], 0, 0, 0);
        }
      __syncthreads();
    }

#pragma unroll
    for (int rr = 0; rr < 2; ++rr) {
      const int r = rr * 2;
      const int lr0 = 16 * wid + q * 4 + r;
      const int pl = lr0 >> 1;
      const f16_t* Prp = P + (long)xvp[rr] * NCOL;
#pragma unroll
      for (int jh = 0; jh < 2; ++jh) {
        const int j = j0 + jh * 16 + l15;
        f16x4 pp = *(const f16x4*)&Prp[j * 4];
        float ipre = (float)pp[0] + acc[0][jh][r] + acc[0][jh][r + 1];
        float opre = (float)pp[1] + acc[1][jh][r] + acc[1][jh][r + 1];
        float upre = (float)pp[2] + acc[2][jh][r] + acc[2][jh][r + 1];
        float pf   = (float)pp[3];
        float fl = sigf(pf + acc[3][jh][r]);
        float fr = sigf(pf + acc[3][jh][r + 1]);
        float clv, crv;
        if (LEAF) {
          clv = (float)Cc[(long)xvl[rr] * HP + j];
          crv = (float)Cc[(long)xvr[rr] * HP + j];
        } else {
          clv = (float)Cc[(long)(2 * p0 + lr0) * HP + j];
          crv = (float)Cc[(long)(2 * p0 + lr0 + 1) * HP + j];
        }
        float cn = sigf(ipre) * tanhf_(upre) + fl * clv + fr * crv;
        float hn = sigf(opre) * tanhf_(cn);
        A2_sh[pl * AST + j] = (f16_t)hn;
        C_sh[pl * 160 + j] = (f16_t)cn;
        int wbase = (j < 150) ? j * 5 : 0;
#pragma unroll
        for (int m = 0; m < 5; ++m) oacc1[rr][m] += hn * W_out[wbase + m];
      }
    }
  }

#pragma unroll
  for (int rr = 0; rr < 2; ++rr) {
    int pl = 8 * wid + 2 * q + rr;
#pragma unroll
    for (int m = 0; m < 5; ++m) {
      float v = oacc1[rr][m];
      v += __shfl_xor(v, 1);
      v += __shfl_xor(v, 2);
      v += __shfl_xor(v, 4);
      v += __shfl_xor(v, 8);
      if (l15 == 0) out[((long)s1 + p0 + pl) * 5 + m] = v + b_out[m];
    }
  }

  const int s2 = (s1 - 1) >> 1;
  const int p02 = p0 >> 1;
  const bool act2 = (wid < 2);
  int xvp2[2];
#pragma unroll
  for (int rr = 0; rr < 2; ++rr) {
    int pl = 8 * wid + 2 * q + rr;
    long pn = (long)s2 + p02 + (act2 ? pl : 0);
    xvp2[rr] = x_id[pn];
  }
  float oacc2[2][5] = {};

  for (int jt = 0; jt < 5; ++jt) {
    const int j0 = jt * 32;
    f32x4 acc[4][2];
#pragma unroll
    for (int g = 0; g < 4; ++g)
#pragma unroll
      for (int jh = 0; jh < 2; ++jh) acc[g][jh] = zero4();

    for (int kk = 0; kk < HP; kk += 32) {
#pragma unroll
      for (int i = 0; i < 2; ++i) {
        int ch = tid + 256 * i;
        int cidx = ch >> 2, kc = (ch & 3) * 8;
        int g = cidx >> 5, jj = cidx & 31;
        int col = g * HP + j0 + jj;
        *(f16x8*)&B_sh[cidx * 40 + kc] = *(const f16x8*)&UreT[col * HP + kk + kc];
      }
      __syncthreads();
      if (act2) {
        f16x8 af = *(const f16x8*)&A2_sh[(16 * wid + l15) * AST + kk + q * 8];
#pragma unroll
        for (int g = 0; g < 4; ++g)
#pragma unroll
          for (int jh = 0; jh < 2; ++jh) {
            f16x8 bfr = *(const f16x8*)&B_sh[(g * 32 + jh * 16 + l15) * 40 + q * 8];
            acc[g][jh] = __builtin_amdgcn_mfma_f32_16x16x32_f16(af, bfr, acc[g][jh], 0, 0, 0);
          }
      }
      __syncthreads();
    }

    if (act2) {
#pragma unroll
      for (int rr = 0; rr < 2; ++rr) {
        const int r = rr * 2;
        const int lr0 = 16 * wid + q * 4 + r;
        const int pl = lr0 >> 1;
        const f16_t* Prp = P + (long)xvp2[rr] * NCOL;
#pragma unroll
        for (int jh = 0; jh < 2; ++jh) {
          const int j = j0 + jh * 16 + l15;
          f16x4 pp = *(const f16x4*)&Prp[j * 4];
          float ipre = (float)pp[0] + acc[0][jh][r] + acc[0][jh][r + 1];
          float opre = (float)pp[1] + acc[1][jh][r] + acc[1][jh][r + 1];
          float upre = (float)pp[2] + acc[2][jh][r] + acc[2][jh][r + 1];
          float pf   = (float)pp[3];
          float fl = sigf(pf + acc[3][jh][r]);
          float fr = sigf(pf + acc[3][jh][r + 1]);
          float clv = (float)C_sh[lr0 * 160 + j];
          float crv = (float)C_sh[(lr0 + 1) * 160 + j];
          float cn = sigf(ipre) * tanhf_(upre) + fl * clv + fr * crv;
          float hn = sigf(opre) * tanhf_(cn);
          Hout[(long)(p02 + pl) * HP + j] = (f16_t)hn;
          Cout[(long)(p02 + pl) * HP + j] = (f16_t)cn;
          int wbase = (j < 150) ? j * 5 : 0;
#pragma unroll
          for (int m = 0; m < 5; ++m) oacc2[rr][m] += hn * W_out[wbase + m];
        }
      }
    }
  }

  if (act2) {
#pragma unroll
    for (int rr = 0; rr < 2; ++rr) {
      int pl = 8 * wid + 2 * q + rr;
#pragma unroll
      for (int m = 0; m < 5; ++m) {
        float v = oacc2[rr][m];
        v += __shfl_xor(v, 1);
        v += __shfl_xor(v, 2);
        v += __shfl_xor(v, 4);
        v += __shfl_xor(v, 8);
        if (l15 == 0) out[((long)s2 + p02 + pl) * 5 + m] = v + b_out[m];
      }
    }
  }
}

// VALU-direct kernel for SMALL levels (M <= 4096): PPB=4 parents per block,
// lane j owns output column j for all 4 parents. U read via UP2 (coalesced:
// lane j loads 16 B contiguous per k-pair, amortized over 4 parents);
// 8 child h rows staged in LDS (2.5 KB), read as wave-uniform broadcasts.
__global__ __launch_bounds__(256) void small_level(
    const int* __restrict__ x_id, const f16_t* __restrict__ P,
    const f16_t* __restrict__ UP2, const f16_t* __restrict__ Hc,
    const f16_t* __restrict__ Cc, f16_t* __restrict__ Hp, f16_t* __restrict__ Cp,
    const float* __restrict__ W_out, const float* __restrict__ b_out,
    float* __restrict__ out, int s, int M) {
  __shared__ __align__(16) f16_t hlr[8 * 160];   // child rows crow0..crow0+7
  __shared__ float partial[4][PPB][5];
  const int tid = threadIdx.x;
  const int pbase = blockIdx.x * PPB;
  const int crow0 = 2 * pbase;
  const int rowsValid = 2 * M - crow0;          // may be < 8 at tiny levels

  if (tid < 160) {
    int r = tid / 20, kc = (tid % 20) * 8;
    f16x8 v = (r < rowsValid) ? *(const f16x8*)&Hc[(long)(crow0 + r) * HP + kc] : zero8();
    *(f16x8*)&hlr[r * 160 + kc] = v;
  }
  __syncthreads();

  const int j = tid;                            // cols 0..159 active
  float ai[PPB], ao[PPB], au[PPB], afl[PPB], afr[PPB];
  float contrib[PPB][5];
#pragma unroll
  for (int pp = 0; pp < PPB; ++pp) {
    ai[pp] = ao[pp] = au[pp] = afl[pp] = afr[pp] = 0.0f;
#pragma unroll
    for (int m = 0; m < 5; ++m) contrib[pp][m] = 0.0f;
  }

  if (j < HP) {
    const f16_t* Uj = UP2 + (long)j * 8;        // row stride 160*8 f16
#pragma unroll 5
    for (int k2 = 0; k2 < 75; ++k2) {           // k = 2*k2, 2*k2+1 (< 150)
      f16x8 u8 = *(const f16x8*)&Uj[(long)k2 * 1280];
      float ui0 = (float)u8[0], uo0 = (float)u8[1], uu0 = (float)u8[2], uf0 = (float)u8[3];
      float ui1 = (float)u8[4], uo1 = (float)u8[5], uu1 = (float)u8[6], uf1 = (float)u8[7];
#pragma unroll
      for (int pp = 0; pp < PPB; ++pp) {
        f16x2 hl2 = *(const f16x2*)&hlr[(2 * pp) * 160 + 2 * k2];
        f16x2 hr2 = *(const f16x2*)&hlr[(2 * pp + 1) * 160 + 2 * k2];
        float hl0 = (float)hl2[0], hl1 = (float)hl2[1];
        float hr0 = (float)hr2[0], hr1 = (float)hr2[1];
        float hs0 = hl0 + hr0, hs1 = hl1 + hr1;
        ai[pp]  += hs0 * ui0 + hs1 * ui1;
        ao[pp]  += hs0 * uo0 + hs1 * uo1;
        au[pp]  += hs0 * uu0 + hs1 * uu1;
        afl[pp] += hl0 * uf0 + hl1 * uf1;
        afr[pp] += hr0 * uf0 + hr1 * uf1;
      }
    }

#pragma unroll
    for (int pp = 0; pp < PPB; ++pp) {
      int p = pbase + pp;
      bool pv = (p < M);
      int xv = x_id[(long)s + (pv ? p : 0)];
      f16x4 ppx = *(const f16x4*)&P[(long)xv * NCOL + j * 4];
      float ipre = (float)ppx[0] + ai[pp];
      float opre = (float)ppx[1] + ao[pp];
      float upre = (float)ppx[2] + au[pp];
      float pf   = (float)ppx[3];
      float fl = sigf(pf + afl[pp]), fr = sigf(pf + afr[pp]);
      float clv = pv ? (float)Cc[(long)(crow0 + 2 * pp) * HP + j] : 0.0f;
      float crv = pv ? (float)Cc[(long)(crow0 + 2 * pp + 1) * HP + j] : 0.0f;
      float cn = sigf(ipre) * tanhf_(upre) + fl * clv + fr * crv;
      float hn = sigf(opre) * tanhf_(cn);
      if (pv) {
        Hp[(long)p * HP + j] = (f16_t)hn;       // pads compute to exactly 0
        Cp[(long)p * HP + j] = (f16_t)cn;
      }
      int wbase = (j < 150) ? j * 5 : 0;        // hn==0 on pads
#pragma unroll
      for (int m = 0; m < 5; ++m) contrib[pp][m] = hn * W_out[wbase + m];
    }
  }

  const int w = tid >> 6, l = tid & 63;
#pragma unroll
  for (int pp = 0; pp < PPB; ++pp)
#pragma unroll
    for (int m = 0; m < 5; ++m) {
      float v = contrib[pp][m];
      v += __shfl_xor(v, 1);  v += __shfl_xor(v, 2);  v += __shfl_xor(v, 4);
      v += __shfl_xor(v, 8);  v += __shfl_xor(v, 16); v += __shfl_xor(v, 32);
      if (l == 0) partial[w][pp][m] = v;
    }
  __syncthreads();
  if (tid < PPB * 5) {
    int pp = tid / 5, m = tid % 5;
    int p = pbase + pp;
    if (p < M) {
      float v = partial[0][pp][m] + partial[1][pp][m] + partial[2][pp][m] + partial[3][pp][m];
      out[((long)s + p) * 5 + m] = v + b_out[m];
    }
  }
}

extern "C" void kernel_launch(void* const* d_in, const int* in_sizes, int n_in,
                              void* d_out, int out_size, void* d_ws, size_t ws_size,
                              hipStream_t stream) {
  const int* x_id   = (const int*)d_in[0];
  const float* emb  = (const float*)d_in[1];
  const float* W_iou = (const float*)d_in[2];
  const float* U_iou = (const float*)d_in[3];
  const float* b_iou = (const float*)d_in[4];
  const float* W_f   = (const float*)d_in[5];
  const float* U_f   = (const float*)d_in[6];
  const float* b_f   = (const float*)d_in[7];
  const float* W_out = (const float*)d_in[8];
  const float* b_out = (const float*)d_in[9];
  float* out = (float*)d_out;
  char* ws = (char*)d_ws;

  // workspace carve (bytes), peak 180,707,840 <= 182,103,040 budget.
  // All region reuses are stream-ordered (writer launched after last reader).
  f16_t* WreT  = (f16_t*)(ws + 0);              // 409,600
  f16_t* UreT  = (f16_t*)(ws + 409600);         // 204,800
  float* bre   = (float*)(ws + 614400);         // 2,560
  f16_t* P     = (f16_t*)(ws + 616960);         // 64,000,000 (persistent)
  f16_t* Hleaf = (f16_t*)(ws + 64616960);       // 16,000,000 (dead after L17)
  f16_t* Cleaf = (f16_t*)(ws + 80616960);       // 16,000,000 (dead after L17)
  float* Oleaf = (float*)(ws + 96616960);       // 1,600,000 (dead after leafout)
  f16_t* H17   = (f16_t*)(ws + 96616960);       // 41,943,040 (131072 rows)
  f16_t* C17   = (f16_t*)(ws + 138560000);      // 41,943,040 -> ends 180,503,040
  f16_t* H15 = (f16_t*)(ws + 64616960);         // 10,485,760 (32768 rows) over Hleaf
  f16_t* C15 = (f16_t*)(ws + 75102720);         // 10,485,760 -> ends 85,588,480
  f16_t* H13 = (f16_t*)(ws + 96616960);         //  2,621,440 (8192 rows) over H17
  f16_t* C13 = (f16_t*)(ws + 99238400);         //  2,621,440
  f16_t* UP2 = (f16_t*)(ws + 180503040);        //    204,800 (persistent)
  // VALU-level buffers: 85,588,480 .. 90,830,720 (after H15/C15 dead).
  char* vb = ws + 85588480;
  f16_t* VH[13]; f16_t* VC[13];
  for (int L = 12; L >= 0; --L) {
    size_t rows = (size_t)1 << L;
    VH[L] = (f16_t*)vb; vb += rows * 320;
    VC[L] = (f16_t*)vb; vb += rows * 320;
  }

  prep_params<<<1603, 256, 0, stream>>>(W_iou, U_iou, b_iou, W_f, U_f, b_f,
                                        WreT, UreT, bre, UP2);
  gemm_p<<<782, 256, 0, stream>>>(emb, WreT, bre, P);
  leafhc_kernel<<<15625, 256, 0, stream>>>(P, Hleaf, Cleaf);
  oleaf_kernel<<<3125, 256, 0, stream>>>(Hleaf, W_out, b_out, Oleaf);
  leafout_kernel<<<1024, 256, 0, stream>>>(x_id, Oleaf, out);

  // level 17 standalone (slim LDS): leaves -> H17/C17
  level17_kernel<<<4096, 256, 0, stream>>>(x_id, P, UreT, Hleaf, Cleaf, H17, C17,
                                           W_out, b_out, out);
  // fused pairs for the big levels:
  fused_kernel<false><<<2048, 256, 0, stream>>>(x_id, P, UreT, H17, C17, H15, C15,
                                                W_out, b_out, out, (1 << 16) - 1, 1 << 16);
  fused_kernel<false><<<512, 256, 0, stream>>>(x_id, P, UreT, H15, C15, H13, C13,
                                               W_out, b_out, out, (1 << 14) - 1, 1 << 14);
  // VALU-direct small levels 12..0 (PPB parents per block):
  small_level<<<1024, 256, 0, stream>>>(x_id, P, UP2, H13, C13, VH[12], VC[12],
                                        W_out, b_out, out, (1 << 12) - 1, 1 << 12);
  for (int L = 11; L >= 0; --L) {
    int M = 1 << L;
    int nb = (M + PPB - 1) / PPB;
    small_level<<<nb, 256, 0, stream>>>(x_id, P, UP2, VH[L + 1], VC[L + 1],
                                        VH[L], VC[L], W_out, b_out, out,
                                        M - 1, M);
  }

  (void)in_sizes; (void)n_in; (void)out_size; (void)ws_size;
}

// Round 7
// 886.044 us; speedup vs baseline: 1.1188x; 1.0723x over previous
//
#include <hip/hip_runtime.h>
#include <cstdint>

typedef _Float16 f16_t;
typedef __attribute__((ext_vector_type(8))) _Float16 f16x8;
typedef __attribute__((ext_vector_type(4))) _Float16 f16x4;
typedef __attribute__((ext_vector_type(2))) _Float16 f16x2;
typedef __attribute__((ext_vector_type(4))) float f32x4;

#define HP      160      // padded H (150 -> 160): h/c row stride, U K-dim
#define NCOL    640      // 160 j x 4 gates (P is [v][j][g] interleaved)
#define KXP     320      // padded X_SIZE (300 -> 320)
#define NNODES  524287
#define LEAF_S  262143
#define LEAF_M  262144
#define NVOCAB  50000
#define AST     168      // A_sh stride (f16): 16B-aligned, 2-way-bank-free
#define PPB     4        // parents per block in small_level

__device__ __forceinline__ float frcp(float x) { return __builtin_amdgcn_rcpf(x); }
__device__ __forceinline__ float sigf(float x) { return frcp(1.0f + __expf(-x)); }
__device__ __forceinline__ float tanhf_(float x) {
  return 1.0f - 2.0f * frcp(1.0f + __expf(2.0f * x));
}
__device__ __forceinline__ f16x8 zero8() {
  f16x8 z;
#pragma unroll
  for (int i = 0; i < 8; ++i) z[i] = (_Float16)0.0f;
  return z;
}
__device__ __forceinline__ f32x4 zero4() {
  f32x4 z;
#pragma unroll
  for (int i = 0; i < 4; ++i) z[i] = 0.0f;
  return z;
}

// WreT[colIdx][k], colIdx = j*4+g (interleaved, matches P);
// UreT[col][k], col = g*160+j (g-major, matches B staging); bre interleaved.
// UP2[(k2*160+j)*8 + (k&1)*4 + g]: coalesced-by-j layout for small_level.
__global__ void prep_params(const float* __restrict__ W_iou, const float* __restrict__ U_iou,
                            const float* __restrict__ b_iou, const float* __restrict__ W_f,
                            const float* __restrict__ U_f, const float* __restrict__ b_f,
                            f16_t* __restrict__ WreT, f16_t* __restrict__ UreT,
                            float* __restrict__ bre, f16_t* __restrict__ UP2) {
  int idx = blockIdx.x * 256 + threadIdx.x;
  if (idx < NCOL * KXP) {
    int col = idx / KXP, k = idx % KXP;
    int j = col >> 2, g = col & 3;
    float v = 0.0f;
    if (k < 300 && j < 150) v = (g < 3) ? W_iou[k * 450 + g * 150 + j] : W_f[k * 150 + j];
    WreT[idx] = (f16_t)v;
  } else if (idx < NCOL * KXP + NCOL * HP) {
    int i2 = idx - NCOL * KXP;
    int col = i2 / HP, k = i2 % HP;
    int g = col / 160, j = col % 160;
    float v = 0.0f;
    if (k < 150 && j < 150) v = (g < 3) ? U_iou[k * 450 + g * 150 + j] : U_f[k * 150 + j];
    UreT[i2] = (f16_t)v;
  } else if (idx < NCOL * KXP + NCOL * HP + NCOL) {
    int col = idx - (NCOL * KXP + NCOL * HP);
    int j = col >> 2, g = col & 3;
    bre[col] = (j < 150) ? ((g < 3) ? b_iou[g * 150 + j] : b_f[j]) : 0.0f;
  } else if (idx < NCOL * KXP + NCOL * HP + NCOL + NCOL * HP) {
    int i3 = idx - (NCOL * KXP + NCOL * HP + NCOL);
    int slot = i3 & 7, t = i3 >> 3;
    int j = t % 160, k2 = t / 160;
    int k = 2 * k2 + (slot >> 2), g = slot & 3;
    float v = 0.0f;
    if (k < 150 && j < 150) v = (g < 3) ? U_iou[k * 450 + g * 150 + j] : U_f[k * 150 + j];
    UP2[i3] = (f16_t)v;
  }
}

// P[v][j][g] = emb @ W + b, fp16, 50000 x 640 (interleaved cols).
__global__ __launch_bounds__(256) void gemm_p(const float* __restrict__ emb,
                                              const f16_t* __restrict__ WreT,
                                              const float* __restrict__ bre,
                                              f16_t* __restrict__ P) {
  __shared__ __align__(16) f16_t A_sh[64 * 328];
  __shared__ __align__(16) f16_t B_sh[128 * 40];
  const int tid = threadIdx.x;
  const int wid = tid >> 6, lane = tid & 63, l15 = lane & 15, q = lane >> 4;
  const int row0 = blockIdx.x * 64;

#pragma unroll
  for (int i = 0; i < 10; ++i) {
    int ch = tid + 256 * i;
    int r = ch / 40, kc = (ch % 40) * 8;
    int grow = row0 + r;
    f16x8 hv;
    if (grow < NVOCAB && kc + 8 <= 300) {
      float4 a = *(const float4*)&emb[grow * 300 + kc];
      float4 b = *(const float4*)&emb[grow * 300 + kc + 4];
      hv[0] = (_Float16)a.x; hv[1] = (_Float16)a.y; hv[2] = (_Float16)a.z; hv[3] = (_Float16)a.w;
      hv[4] = (_Float16)b.x; hv[5] = (_Float16)b.y; hv[6] = (_Float16)b.z; hv[7] = (_Float16)b.w;
    } else {
#pragma unroll
      for (int e = 0; e < 8; ++e) {
        int k = kc + e;
        float v = (grow < NVOCAB && k < 300) ? emb[grow * 300 + k] : 0.0f;
        hv[e] = (_Float16)v;
      }
    }
    *(f16x8*)&A_sh[r * 328 + kc] = hv;
  }
  __syncthreads();

  for (int bn = 0; bn < 5; ++bn) {
    const int col0 = bn * 128;
    f32x4 acc[8];
#pragma unroll
    for (int t = 0; t < 8; ++t) acc[t] = zero4();
    for (int kk = 0; kk < KXP; kk += 32) {
#pragma unroll
      for (int i = 0; i < 2; ++i) {
        int ch = tid + 256 * i;
        int cidx = ch >> 2, kc = (ch & 3) * 8;
        *(f16x8*)&B_sh[cidx * 40 + kc] =
            *(const f16x8*)&WreT[(col0 + cidx) * KXP + kk + kc];
      }
      __syncthreads();
      f16x8 af = *(const f16x8*)&A_sh[(16 * wid + l15) * 328 + kk + q * 8];
#pragma unroll
      for (int t = 0; t < 8; ++t) {
        f16x8 bfr = *(const f16x8*)&B_sh[(t * 16 + l15) * 40 + q * 8];
        acc[t] = __builtin_amdgcn_mfma_f32_16x16x32_f16(af, bfr, acc[t], 0, 0, 0);
      }
      __syncthreads();
    }
#pragma unroll
    for (int t = 0; t < 8; ++t) {
      int col = col0 + t * 16 + l15;
      float bias = bre[col];
#pragma unroll
      for (int r2 = 0; r2 < 4; ++r2) {
        int row = row0 + 16 * wid + q * 4 + r2;
        if (row < NVOCAB) P[(long)row * NCOL + col] = (f16_t)(acc[t][r2] + bias);
      }
    }
  }
}

// Vocab-space leaf h/c tables: Hleaf[v][j], Cleaf[v][j] (f16).
__global__ void leafhc_kernel(const f16_t* __restrict__ P, f16_t* __restrict__ Hleaf,
                              f16_t* __restrict__ Cleaf) {
  int idx = blockIdx.x * 256 + threadIdx.x;
  if (idx >= NVOCAB * 80) return;
  int v = idx / 80, t = idx % 80;
  f16x8 pk = *(const f16x8*)&P[(long)v * NCOL + t * 8];
#pragma unroll
  for (int e = 0; e < 2; ++e) {
    float iv = (float)pk[e * 4 + 0], ov = (float)pk[e * 4 + 1], uv = (float)pk[e * 4 + 2];
    float cl = sigf(iv) * tanhf_(uv);
    float hl = sigf(ov) * tanhf_(cl);
    Hleaf[(long)v * HP + t * 2 + e] = (f16_t)hl;   // pads (t>=75) stay exactly 0
    Cleaf[(long)v * HP + t * 2 + e] = (f16_t)cl;
  }
}

// Oleaf[v] = Hleaf[v] @ W_out + b_out (row stride 8 floats for alignment).
__global__ void oleaf_kernel(const f16_t* __restrict__ Hleaf, const float* __restrict__ W_out,
                             const float* __restrict__ b_out, float* __restrict__ Oleaf) {
  const int tid = threadIdx.x;
  const int row = blockIdx.x * 16 + (tid >> 4), l = tid & 15;
  if (row >= NVOCAB) return;
  float acc[5] = {0, 0, 0, 0, 0};
  for (int j = l; j < 150; j += 16) {
    float hv = (float)Hleaf[(long)row * HP + j];
#pragma unroll
    for (int m = 0; m < 5; ++m) acc[m] += hv * W_out[j * 5 + m];
  }
#pragma unroll
  for (int m = 0; m < 5; ++m) {
    float vv = acc[m];
    vv += __shfl_xor(vv, 1);
    vv += __shfl_xor(vv, 2);
    vv += __shfl_xor(vv, 4);
    vv += __shfl_xor(vv, 8);
    if (l == 0) Oleaf[(long)row * 8 + m] = vv + b_out[m];
  }
}

// Leaf output rows: pure 20B gather from Oleaf.
__global__ void leafout_kernel(const int* __restrict__ x_id, const float* __restrict__ Oleaf,
                               float* __restrict__ out) {
  int leaf = blockIdx.x * 256 + threadIdx.x;
  int xv = x_id[LEAF_S + leaf];
  const float* O = Oleaf + (long)xv * 8;
  float4 o4 = *(const float4*)O;
  float o5 = O[4];
  long base = ((long)LEAF_S + leaf) * 5;
  out[base + 0] = o4.x; out[base + 1] = o4.y; out[base + 2] = o4.z;
  out[base + 3] = o4.w; out[base + 4] = o5;
}

// Single-level kernel for LEVEL 17 ONLY: 262144 leaves -> 131072 parents.
__global__ __launch_bounds__(256, 3) void level17_kernel(
    const int* __restrict__ x_id, const f16_t* __restrict__ P,
    const f16_t* __restrict__ UreT, const f16_t* __restrict__ Hleaf,
    const f16_t* __restrict__ Cleaf, f16_t* __restrict__ Hout,
    f16_t* __restrict__ Cout, const float* __restrict__ W_out,
    const float* __restrict__ b_out, float* __restrict__ out) {
  __shared__ __align__(16) f16_t A_sh[64 * AST];
  __shared__ __align__(16) f16_t B_sh[128 * 40];
  const int tid = threadIdx.x;
  const int wid = tid >> 6, lane = tid & 63, l15 = lane & 15, q = lane >> 4;
  const int p0 = blockIdx.x * 32;
  const int s1 = (1 << 17) - 1;                  // 131071
  const long childbase = 2L * s1 + 1 + 2 * p0;   // first child (leaf) node id

#pragma unroll
  for (int i = 0; i < 5; ++i) {
    int ch = tid + 256 * i;
    int r = ch / 20, kc = (ch % 20) * 8;
    int xv = x_id[childbase + r];
    *(f16x8*)&A_sh[r * AST + kc] = *(const f16x8*)&Hleaf[(long)xv * HP + kc];
  }
  __syncthreads();

  int xvp[2], xvl[2], xvr[2];
#pragma unroll
  for (int rr = 0; rr < 2; ++rr) {
    int pl = 8 * wid + 2 * q + rr;
    xvp[rr] = x_id[(long)s1 + p0 + pl];
    xvl[rr] = x_id[childbase + 2 * pl];
    xvr[rr] = x_id[childbase + 2 * pl + 1];
  }
  float oacc[2][5] = {};

  for (int jt = 0; jt < 5; ++jt) {
    const int j0 = jt * 32;
    f32x4 acc[4][2];
#pragma unroll
    for (int g = 0; g < 4; ++g)
#pragma unroll
      for (int jh = 0; jh < 2; ++jh) acc[g][jh] = zero4();

    for (int kk = 0; kk < HP; kk += 32) {
#pragma unroll
      for (int i = 0; i < 2; ++i) {
        int ch = tid + 256 * i;
        int cidx = ch >> 2, kc = (ch & 3) * 8;
        int g = cidx >> 5, jj = cidx & 31;
        int col = g * HP + j0 + jj;
        *(f16x8*)&B_sh[cidx * 40 + kc] = *(const f16x8*)&UreT[col * HP + kk + kc];
      }
      __syncthreads();
      f16x8 af = *(const f16x8*)&A_sh[(16 * wid + l15) * AST + kk + q * 8];
#pragma unroll
      for (int g = 0; g < 4; ++g)
#pragma unroll
        for (int jh = 0; jh < 2; ++jh) {
          f16x8 bfr = *(const f16x8*)&B_sh[(g * 32 + jh * 16 + l15) * 40 + q * 8];
          acc[g][jh] = __builtin_amdgcn_mfma_f32_16x16x32_f16(af, bfr, acc[g][jh], 0, 0, 0);
        }
      __syncthreads();
    }

#pragma unroll
    for (int rr = 0; rr < 2; ++rr) {
      const int r = rr * 2;
      const int pl = 8 * wid + 2 * q + rr;      // local parent 0..31
      const f16_t* Prp = P + (long)xvp[rr] * NCOL;
#pragma unroll
      for (int jh = 0; jh < 2; ++jh) {
        const int j = j0 + jh * 16 + l15;
        f16x4 pp = *(const f16x4*)&Prp[j * 4];
        float ipre = (float)pp[0] + acc[0][jh][r] + acc[0][jh][r + 1];
        float opre = (float)pp[1] + acc[1][jh][r] + acc[1][jh][r + 1];
        float upre = (float)pp[2] + acc[2][jh][r] + acc[2][jh][r + 1];
        float pf   = (float)pp[3];
        float fl = sigf(pf + acc[3][jh][r]);
        float fr = sigf(pf + acc[3][jh][r + 1]);
        float clv = (float)Cleaf[(long)xvl[rr] * HP + j];
        float crv = (float)Cleaf[(long)xvr[rr] * HP + j];
        float cn = sigf(ipre) * tanhf_(upre) + fl * clv + fr * crv;
        float hn = sigf(opre) * tanhf_(cn);
        Hout[(long)(p0 + pl) * HP + j] = (f16_t)hn;   // pads stay exactly 0
        Cout[(long)(p0 + pl) * HP + j] = (f16_t)cn;
        int wbase = (j < 150) ? j * 5 : 0;            // hn==0 on pads
#pragma unroll
        for (int m = 0; m < 5; ++m) oacc[rr][m] += hn * W_out[wbase + m];
      }
    }
  }

#pragma unroll
  for (int rr = 0; rr < 2; ++rr) {
    int pl = 8 * wid + 2 * q + rr;
#pragma unroll
    for (int m = 0; m < 5; ++m) {
      float v = oacc[rr][m];
      v += __shfl_xor(v, 1);
      v += __shfl_xor(v, 2);
      v += __shfl_xor(v, 4);
      v += __shfl_xor(v, 8);
      if (l15 == 0) out[((long)s1 + p0 + pl) * 5 + m] = v + b_out[m];
    }
  }
}

// Two fused levels per block (round-0 proven structure).
template <bool LEAF>
__global__ __launch_bounds__(256, 3) void fused_kernel(
    const int* __restrict__ x_id, const f16_t* __restrict__ P,
    const f16_t* __restrict__ UreT, const f16_t* __restrict__ Hc,
    const f16_t* __restrict__ Cc, f16_t* __restrict__ Hout,
    f16_t* __restrict__ Cout, const float* __restrict__ W_out,
    const float* __restrict__ b_out, float* __restrict__ out, int s1, int M1) {
  __shared__ __align__(16) f16_t A_sh[64 * AST];
  __shared__ __align__(16) f16_t A2_sh[32 * AST];
  __shared__ __align__(16) f16_t B_sh[128 * 40];
  __shared__ f16_t C_sh[32 * 160];
  const int tid = threadIdx.x;
  const int wid = tid >> 6, lane = tid & 63, l15 = lane & 15, q = lane >> 4;
  const int p0 = blockIdx.x * 32;
  const long childbase = 2L * s1 + 1 + 2 * p0;

#pragma unroll
  for (int i = 0; i < 5; ++i) {
    int ch = tid + 256 * i;
    int r = ch / 20, kc = (ch % 20) * 8;
    f16x8 v;
    if (LEAF) {
      int xv = x_id[childbase + r];
      v = *(const f16x8*)&Hc[(long)xv * HP + kc];
    } else {
      v = *(const f16x8*)&Hc[(long)(2 * p0 + r) * HP + kc];
    }
    *(f16x8*)&A_sh[r * AST + kc] = v;
  }
  __syncthreads();

  int xvp[2], xvl[2], xvr[2];
#pragma unroll
  for (int rr = 0; rr < 2; ++rr) {
    int pl = 8 * wid + 2 * q + rr;
    long pn = (long)s1 + p0 + pl;
    xvp[rr] = x_id[pn];
    if (LEAF) {
      xvl[rr] = x_id[childbase + 2 * pl];
      xvr[rr] = x_id[childbase + 2 * pl + 1];
    }
  }
  float oacc1[2][5] = {};

  for (int jt = 0; jt < 5; ++jt) {
    const int j0 = jt * 32;
    f32x4 acc[4][2];
#pragma unroll
    for (int g = 0; g < 4; ++g)
#pragma unroll
      for (int jh = 0; jh < 2; ++jh) acc[g][jh] = zero4();

    for (int kk = 0; kk < HP; kk += 32) {
#pragma unroll
      for (int i = 0; i < 2; ++i) {
        int ch = tid + 256 * i;
        int cidx = ch >> 2, kc = (ch & 3) * 8;
        int g = cidx >> 5, jj = cidx & 31;
        int col = g * HP + j0 + jj;
        *(f16x8*)&B_sh[cidx * 40 + kc] = *(const f16x8*)&UreT[col * HP + kk + kc];
      }
      __syncthreads();
      f16x8 af = *(const f16x8*)&A_sh[(16 * wid + l15) * AST + kk + q * 8];
#pragma unroll
      for (int g = 0; g < 4; ++g)
#pragma unroll
        for (int jh = 0; jh < 2; ++jh) {
          f16x8 bfr = *(const f16x8*)&B_sh[(g * 32 + jh * 16 + l15) * 40 + q * 8];
          acc[g][jh] = __builtin_amdgcn_mfma_f32_16x16x32_f16(af, bfr, acc[g][jh], 0, 0, 0);
        }
      __syncthreads();
    }

#pragma unroll
    for (int rr = 0; rr < 2; ++rr) {
      const int r = rr * 2;
      const int lr0 = 16 * wid + q * 4 + r;
      const int pl = lr0 >> 1;
      const f16_t* Prp = P + (long)xvp[rr] * NCOL;
#pragma unroll
      for (int jh = 0; jh < 2; ++jh) {
        const int j = j0 + jh * 16 + l15;
        f16x4 pp = *(const f16x4*)&Prp[j * 4];
        float ipre = (float)pp[0] + acc[0][jh][r] + acc[0][jh][r + 1];
        float opre = (float)pp[1] + acc[1][jh][r] + acc[1][jh][r + 1];
        float upre = (float)pp[2] + acc[2][jh][r] + acc[2][jh][r + 1];
        float pf   = (float)pp[3];
        float fl = sigf(pf + acc[3][jh][r]);
        float fr = sigf(pf + acc[3][jh][r + 1]);
        float clv, crv;
        if (LEAF) {
          clv = (float)Cc[(long)xvl[rr] * HP + j];
          crv = (float)Cc[(long)xvr[rr] * HP + j];
        } else {
          clv = (float)Cc[(long)(2 * p0 + lr0) * HP + j];
          crv = (float)Cc[(long)(2 * p0 + lr0 + 1) * HP + j];
        }
        float cn = sigf(ipre) * tanhf_(upre) + fl * clv + fr * crv;
        float hn = sigf(opre) * tanhf_(cn);
        A2_sh[pl * AST + j] = (f16_t)hn;
        C_sh[pl * 160 + j] = (f16_t)cn;
        int wbase = (j < 150) ? j * 5 : 0;
#pragma unroll
        for (int m = 0; m < 5; ++m) oacc1[rr][m] += hn * W_out[wbase + m];
      }
    }
  }

#pragma unroll
  for (int rr = 0; rr < 2; ++rr) {
    int pl = 8 * wid + 2 * q + rr;
#pragma unroll
    for (int m = 0; m < 5; ++m) {
      float v = oacc1[rr][m];
      v += __shfl_xor(v, 1);
      v += __shfl_xor(v, 2);
      v += __shfl_xor(v, 4);
      v += __shfl_xor(v, 8);
      if (l15 == 0) out[((long)s1 + p0 + pl) * 5 + m] = v + b_out[m];
    }
  }

  const int s2 = (s1 - 1) >> 1;
  const int p02 = p0 >> 1;
  const bool act2 = (wid < 2);
  int xvp2[2];
#pragma unroll
  for (int rr = 0; rr < 2; ++rr) {
    int pl = 8 * wid + 2 * q + rr;
    long pn = (long)s2 + p02 + (act2 ? pl : 0);
    xvp2[rr] = x_id[pn];
  }
  float oacc2[2][5] = {};

  for (int jt = 0; jt < 5; ++jt) {
    const int j0 = jt * 32;
    f32x4 acc[4][2];
#pragma unroll
    for (int g = 0; g < 4; ++g)
#pragma unroll
      for (int jh = 0; jh < 2; ++jh) acc[g][jh] = zero4();

    for (int kk = 0; kk < HP; kk += 32) {
#pragma unroll
      for (int i = 0; i < 2; ++i) {
        int ch = tid + 256 * i;
        int cidx = ch >> 2, kc = (ch & 3) * 8;
        int g = cidx >> 5, jj = cidx & 31;
        int col = g * HP + j0 + jj;
        *(f16x8*)&B_sh[cidx * 40 + kc] = *(const f16x8*)&UreT[col * HP + kk + kc];
      }
      __syncthreads();
      if (act2) {
        f16x8 af = *(const f16x8*)&A2_sh[(16 * wid + l15) * AST + kk + q * 8];
#pragma unroll
        for (int g = 0; g < 4; ++g)
#pragma unroll
          for (int jh = 0; jh < 2; ++jh) {
            f16x8 bfr = *(const f16x8*)&B_sh[(g * 32 + jh * 16 + l15) * 40 + q * 8];
            acc[g][jh] = __builtin_amdgcn_mfma_f32_16x16x32_f16(af, bfr, acc[g][jh], 0, 0, 0);
          }
      }
      __syncthreads();
    }

    if (act2) {
#pragma unroll
      for (int rr = 0; rr < 2; ++rr) {
        const int r = rr * 2;
        const int lr0 = 16 * wid + q * 4 + r;
        const int pl = lr0 >> 1;
        const f16_t* Prp = P + (long)xvp2[rr] * NCOL;
#pragma unroll
        for (int jh = 0; jh < 2; ++jh) {
          const int j = j0 + jh * 16 + l15;
          f16x4 pp = *(const f16x4*)&Prp[j * 4];
          float ipre = (float)pp[0] + acc[0][jh][r] + acc[0][jh][r + 1];
          float opre = (float)pp[1] + acc[1][jh][r] + acc[1][jh][r + 1];
          float upre = (float)pp[2] + acc[2][jh][r] + acc[2][jh][r + 1];
          float pf   = (float)pp[3];
          float fl = sigf(pf + acc[3][jh][r]);
          float fr = sigf(pf + acc[3][jh][r + 1]);
          float clv = (float)C_sh[lr0 * 160 + j];
          float crv = (float)C_sh[(lr0 + 1) * 160 + j];
          float cn = sigf(ipre) * tanhf_(upre) + fl * clv + fr * crv;
          float hn = sigf(opre) * tanhf_(cn);
          Hout[(long)(p02 + pl) * HP + j] = (f16_t)hn;
          Cout[(long)(p02 + pl) * HP + j] = (f16_t)cn;
          int wbase = (j < 150) ? j * 5 : 0;
#pragma unroll
          for (int m = 0; m < 5; ++m) oacc2[rr][m] += hn * W_out[wbase + m];
        }
      }
    }
  }

  if (act2) {
#pragma unroll
    for (int rr = 0; rr < 2; ++rr) {
      int pl = 8 * wid + 2 * q + rr;
#pragma unroll
      for (int m = 0; m < 5; ++m) {
        float v = oacc2[rr][m];
        v += __shfl_xor(v, 1);
        v += __shfl_xor(v, 2);
        v += __shfl_xor(v, 4);
        v += __shfl_xor(v, 8);
        if (l15 == 0) out[((long)s2 + p02 + pl) * 5 + m] = v + b_out[m];
      }
    }
  }
}

// VALU-direct kernel for TINY levels (M <= 256): PPB=4 parents per block,
// lane j owns output column j for all 4 parents. U via UP2 (coalesced);
// 8 child h rows staged in LDS. Used only where grid is so small that the
// MFMA kernels' ~55 us barrier-phased critical path dominates.
__global__ __launch_bounds__(256) void small_level(
    const int* __restrict__ x_id, const f16_t* __restrict__ P,
    const f16_t* __restrict__ UP2, const f16_t* __restrict__ Hc,
    const f16_t* __restrict__ Cc, f16_t* __restrict__ Hp, f16_t* __restrict__ Cp,
    const float* __restrict__ W_out, const float* __restrict__ b_out,
    float* __restrict__ out, int s, int M) {
  __shared__ __align__(16) f16_t hlr[8 * 160];   // child rows crow0..crow0+7
  __shared__ float partial[4][PPB][5];
  const int tid = threadIdx.x;
  const int pbase = blockIdx.x * PPB;
  const int crow0 = 2 * pbase;
  const int rowsValid = 2 * M - crow0;          // may be < 8 at tiny levels

  if (tid < 160) {
    int r = tid / 20, kc = (tid % 20) * 8;
    f16x8 v = (r < rowsValid) ? *(const f16x8*)&Hc[(long)(crow0 + r) * HP + kc] : zero8();
    *(f16x8*)&hlr[r * 160 + kc] = v;
  }
  __syncthreads();

  const int j = tid;                            // cols 0..159 active
  float ai[PPB], ao[PPB], au[PPB], afl[PPB], afr[PPB];
  float contrib[PPB][5];
#pragma unroll
  for (int pp = 0; pp < PPB; ++pp) {
    ai[pp] = ao[pp] = au[pp] = afl[pp] = afr[pp] = 0.0f;
#pragma unroll
    for (int m = 0; m < 5; ++m) contrib[pp][m] = 0.0f;
  }

  if (j < HP) {
    const f16_t* Uj = UP2 + (long)j * 8;        // row stride 160*8 f16
#pragma unroll 5
    for (int k2 = 0; k2 < 75; ++k2) {           // k = 2*k2, 2*k2+1 (< 150)
      f16x8 u8 = *(const f16x8*)&Uj[(long)k2 * 1280];
      float ui0 = (float)u8[0], uo0 = (float)u8[1], uu0 = (float)u8[2], uf0 = (float)u8[3];
      float ui1 = (float)u8[4], uo1 = (float)u8[5], uu1 = (float)u8[6], uf1 = (float)u8[7];
#pragma unroll
      for (int pp = 0; pp < PPB; ++pp) {
        f16x2 hl2 = *(const f16x2*)&hlr[(2 * pp) * 160 + 2 * k2];
        f16x2 hr2 = *(const f16x2*)&hlr[(2 * pp + 1) * 160 + 2 * k2];
        float hl0 = (float)hl2[0], hl1 = (float)hl2[1];
        float hr0 = (float)hr2[0], hr1 = (float)hr2[1];
        float hs0 = hl0 + hr0, hs1 = hl1 + hr1;
        ai[pp]  += hs0 * ui0 + hs1 * ui1;
        ao[pp]  += hs0 * uo0 + hs1 * uo1;
        au[pp]  += hs0 * uu0 + hs1 * uu1;
        afl[pp] += hl0 * uf0 + hl1 * uf1;
        afr[pp] += hr0 * uf0 + hr1 * uf1;
      }
    }

#pragma unroll
    for (int pp = 0; pp < PPB; ++pp) {
      int p = pbase + pp;
      bool pv = (p < M);
      int xv = x_id[(long)s + (pv ? p : 0)];
      f16x4 ppx = *(const f16x4*)&P[(long)xv * NCOL + j * 4];
      float ipre = (float)ppx[0] + ai[pp];
      float opre = (float)ppx[1] + ao[pp];
      float upre = (float)ppx[2] + au[pp];
      float pf   = (float)ppx[3];
      float fl = sigf(pf + afl[pp]), fr = sigf(pf + afr[pp]);
      float clv = pv ? (float)Cc[(long)(crow0 + 2 * pp) * HP + j] : 0.0f;
      float crv = pv ? (float)Cc[(long)(crow0 + 2 * pp + 1) * HP + j] : 0.0f;
      float cn = sigf(ipre) * tanhf_(upre) + fl * clv + fr * crv;
      float hn = sigf(opre) * tanhf_(cn);
      if (pv) {
        Hp[(long)p * HP + j] = (f16_t)hn;       // pads compute to exactly 0
        Cp[(long)p * HP + j] = (f16_t)cn;
      }
      int wbase = (j < 150) ? j * 5 : 0;        // hn==0 on pads
#pragma unroll
      for (int m = 0; m < 5; ++m) contrib[pp][m] = hn * W_out[wbase + m];
    }
  }

  const int w = tid >> 6, l = tid & 63;
#pragma unroll
  for (int pp = 0; pp < PPB; ++pp)
#pragma unroll
    for (int m = 0; m < 5; ++m) {
      float v = contrib[pp][m];
      v += __shfl_xor(v, 1);  v += __shfl_xor(v, 2);  v += __shfl_xor(v, 4);
      v += __shfl_xor(v, 8);  v += __shfl_xor(v, 16); v += __shfl_xor(v, 32);
      if (l == 0) partial[w][pp][m] = v;
    }
  __syncthreads();
  if (tid < PPB * 5) {
    int pp = tid / 5, m = tid % 5;
    int p = pbase + pp;
    if (p < M) {
      float v = partial[0][pp][m] + partial[1][pp][m] + partial[2][pp][m] + partial[3][pp][m];
      out[((long)s + p) * 5 + m] = v + b_out[m];
    }
  }
}

extern "C" void kernel_launch(void* const* d_in, const int* in_sizes, int n_in,
                              void* d_out, int out_size, void* d_ws, size_t ws_size,
                              hipStream_t stream) {
  const int* x_id   = (const int*)d_in[0];
  const float* emb  = (const float*)d_in[1];
  const float* W_iou = (const float*)d_in[2];
  const float* U_iou = (const float*)d_in[3];
  const float* b_iou = (const float*)d_in[4];
  const float* W_f   = (const float*)d_in[5];
  const float* U_f   = (const float*)d_in[6];
  const float* b_f   = (const float*)d_in[7];
  const float* W_out = (const float*)d_in[8];
  const float* b_out = (const float*)d_in[9];
  float* out = (float*)d_out;
  char* ws = (char*)d_ws;

  // workspace carve (bytes), peak 180,707,840 <= 182,103,040 budget.
  // All region reuses are stream-ordered (writer launched after last reader).
  f16_t* WreT  = (f16_t*)(ws + 0);              // 409,600
  f16_t* UreT  = (f16_t*)(ws + 409600);         // 204,800
  float* bre   = (float*)(ws + 614400);         // 2,560
  f16_t* P     = (f16_t*)(ws + 616960);         // 64,000,000 (persistent)
  f16_t* Hleaf = (f16_t*)(ws + 64616960);       // 16,000,000 (dead after L17)
  f16_t* Cleaf = (f16_t*)(ws + 80616960);       // 16,000,000 (dead after L17)
  float* Oleaf = (float*)(ws + 96616960);       // 1,600,000 (dead after leafout)
  f16_t* H17   = (f16_t*)(ws + 96616960);       // 41,943,040 (131072 rows)
  f16_t* C17   = (f16_t*)(ws + 138560000);      // 41,943,040 -> ends 180,503,040
  f16_t* H15 = (f16_t*)(ws + 64616960);         // 10,485,760 (32768 rows) over Hleaf
  f16_t* C15 = (f16_t*)(ws + 75102720);         // 10,485,760 -> ends 85,588,480
  f16_t* H13 = (f16_t*)(ws + 96616960);         //  2,621,440 (8192 rows) over H17
  f16_t* C13 = (f16_t*)(ws + 99238400);         //  2,621,440
  f16_t* H11 = (f16_t*)(ws + 64616960);         //    655,360 (2048 rows) over H15 (dead)
  f16_t* C11 = (f16_t*)(ws + 65272320);         //    655,360
  f16_t* H9  = (f16_t*)(ws + 96616960);         //    163,840 (512 rows) over H13 (dead)
  f16_t* C9  = (f16_t*)(ws + 96780800);         //    163,840
  f16_t* UP2 = (f16_t*)(ws + 180503040);        //    204,800 (persistent)
  // VALU-level buffers for L8..L0: over dead C15 region (85,588,480+).
  char* vb = ws + 85588480;
  f16_t* VH[9]; f16_t* VC[9];
  for (int L = 8; L >= 0; --L) {
    size_t rows = (size_t)1 << L;
    VH[L] = (f16_t*)vb; vb += rows * 320;
    VC[L] = (f16_t*)vb; vb += rows * 320;
  }

  prep_params<<<1603, 256, 0, stream>>>(W_iou, U_iou, b_iou, W_f, U_f, b_f,
                                        WreT, UreT, bre, UP2);
  gemm_p<<<782, 256, 0, stream>>>(emb, WreT, bre, P);
  leafhc_kernel<<<15625, 256, 0, stream>>>(P, Hleaf, Cleaf);
  oleaf_kernel<<<3125, 256, 0, stream>>>(Hleaf, W_out, b_out, Oleaf);
  leafout_kernel<<<1024, 256, 0, stream>>>(x_id, Oleaf, out);

  // level 17 standalone (slim LDS): leaves -> H17/C17
  level17_kernel<<<4096, 256, 0, stream>>>(x_id, P, UreT, Hleaf, Cleaf, H17, C17,
                                           W_out, b_out, out);
  // MFMA fused pairs down to L9 (grids large enough to fill the machine):
  fused_kernel<false><<<2048, 256, 0, stream>>>(x_id, P, UreT, H17, C17, H15, C15,
                                                W_out, b_out, out, (1 << 16) - 1, 1 << 16);
  fused_kernel<false><<<512, 256, 0, stream>>>(x_id, P, UreT, H15, C15, H13, C13,
                                               W_out, b_out, out, (1 << 14) - 1, 1 << 14);
  fused_kernel<false><<<128, 256, 0, stream>>>(x_id, P, UreT, H13, C13, H11, C11,
                                               W_out, b_out, out, (1 << 12) - 1, 1 << 12);
  fused_kernel<false><<<32, 256, 0, stream>>>(x_id, P, UreT, H11, C11, H9, C9,
                                              W_out, b_out, out, (1 << 10) - 1, 1 << 10);
  // VALU-direct tiny levels 8..0 (PPB parents per block, ~7 us/launch):
  small_level<<<64, 256, 0, stream>>>(x_id, P, UP2, H9, C9, VH[8], VC[8],
                                      W_out, b_out, out, (1 << 8) - 1, 1 << 8);
  for (int L = 7; L >= 0; --L) {
    int M = 1 << L;
    int nb = (M + PPB - 1) / PPB;
    small_level<<<nb, 256, 0, stream>>>(x_id, P, UP2, VH[L + 1], VC[L + 1],
                                        VH[L], VC[L], W_out, b_out, out,
                                        M - 1, M);
  }

  (void)in_sizes; (void)n_in; (void)out_size; (void)ws_size;
}

// Round 8
// 884.441 us; speedup vs baseline: 1.1208x; 1.0018x over previous
//
#include <hip/hip_runtime.h>
#include <cstdint>

typedef _Float16 f16_t;
typedef __attribute__((ext_vector_type(8))) _Float16 f16x8;
typedef __attribute__((ext_vector_type(4))) _Float16 f16x4;
typedef __attribute__((ext_vector_type(4))) float f32x4;

#define HP      160      // padded H (150 -> 160): h/c row stride, U K-dim
#define NCOL    640      // 160 j x 4 gates (P is [v][j][g] interleaved)
#define KXP     320      // padded X_SIZE (300 -> 320)
#define NNODES  524287
#define LEAF_S  262143
#define LEAF_M  262144
#define NVOCAB  50000
#define AST     168      // A_sh/B_sh stride (f16): 16B-aligned, 2-way-bank-free

__device__ __forceinline__ float frcp(float x) { return __builtin_amdgcn_rcpf(x); }
__device__ __forceinline__ float sigf(float x) { return frcp(1.0f + __expf(-x)); }
__device__ __forceinline__ float tanhf_(float x) {
  return 1.0f - 2.0f * frcp(1.0f + __expf(2.0f * x));
}
__device__ __forceinline__ f16x8 zero8() {
  f16x8 z;
#pragma unroll
  for (int i = 0; i < 8; ++i) z[i] = (_Float16)0.0f;
  return z;
}
__device__ __forceinline__ f32x4 zero4() {
  f32x4 z;
#pragma unroll
  for (int i = 0; i < 4; ++i) z[i] = 0.0f;
  return z;
}

// WreT[colIdx][k], colIdx = j*4+g (interleaved, matches P);
// UreT[col][k], col = g*160+j (g-major, matches B staging); bre interleaved.
__global__ void prep_params(const float* __restrict__ W_iou, const float* __restrict__ U_iou,
                            const float* __restrict__ b_iou, const float* __restrict__ W_f,
                            const float* __restrict__ U_f, const float* __restrict__ b_f,
                            f16_t* __restrict__ WreT, f16_t* __restrict__ UreT,
                            float* __restrict__ bre) {
  int idx = blockIdx.x * 256 + threadIdx.x;
  if (idx < NCOL * KXP) {
    int col = idx / KXP, k = idx % KXP;
    int j = col >> 2, g = col & 3;
    float v = 0.0f;
    if (k < 300 && j < 150) v = (g < 3) ? W_iou[k * 450 + g * 150 + j] : W_f[k * 150 + j];
    WreT[idx] = (f16_t)v;
  } else if (idx < NCOL * KXP + NCOL * HP) {
    int i2 = idx - NCOL * KXP;
    int col = i2 / HP, k = i2 % HP;
    int g = col / 160, j = col % 160;
    float v = 0.0f;
    if (k < 150 && j < 150) v = (g < 3) ? U_iou[k * 450 + g * 150 + j] : U_f[k * 150 + j];
    UreT[i2] = (f16_t)v;
  } else if (idx < NCOL * KXP + NCOL * HP + NCOL) {
    int col = idx - (NCOL * KXP + NCOL * HP);
    int j = col >> 2, g = col & 3;
    bre[col] = (j < 150) ? ((g < 3) ? b_iou[g * 150 + j] : b_f[j]) : 0.0f;
  }
}

// P[v][j][g] = emb @ W + b, fp16, 50000 x 640 (interleaved cols).
__global__ __launch_bounds__(256) void gemm_p(const float* __restrict__ emb,
                                              const f16_t* __restrict__ WreT,
                                              const float* __restrict__ bre,
                                              f16_t* __restrict__ P) {
  __shared__ __align__(16) f16_t A_sh[64 * 328];
  __shared__ __align__(16) f16_t B_sh[128 * 40];
  const int tid = threadIdx.x;
  const int wid = tid >> 6, lane = tid & 63, l15 = lane & 15, q = lane >> 4;
  const int row0 = blockIdx.x * 64;

#pragma unroll
  for (int i = 0; i < 10; ++i) {
    int ch = tid + 256 * i;
    int r = ch / 40, kc = (ch % 40) * 8;
    int grow = row0 + r;
    f16x8 hv;
    if (grow < NVOCAB && kc + 8 <= 300) {
      float4 a = *(const float4*)&emb[grow * 300 + kc];
      float4 b = *(const float4*)&emb[grow * 300 + kc + 4];
      hv[0] = (_Float16)a.x; hv[1] = (_Float16)a.y; hv[2] = (_Float16)a.z; hv[3] = (_Float16)a.w;
      hv[4] = (_Float16)b.x; hv[5] = (_Float16)b.y; hv[6] = (_Float16)b.z; hv[7] = (_Float16)b.w;
    } else {
#pragma unroll
      for (int e = 0; e < 8; ++e) {
        int k = kc + e;
        float v = (grow < NVOCAB && k < 300) ? emb[grow * 300 + k] : 0.0f;
        hv[e] = (_Float16)v;
      }
    }
    *(f16x8*)&A_sh[r * 328 + kc] = hv;
  }
  __syncthreads();

  for (int bn = 0; bn < 5; ++bn) {
    const int col0 = bn * 128;
    f32x4 acc[8];
#pragma unroll
    for (int t = 0; t < 8; ++t) acc[t] = zero4();
    for (int kk = 0; kk < KXP; kk += 32) {
#pragma unroll
      for (int i = 0; i < 2; ++i) {
        int ch = tid + 256 * i;
        int cidx = ch >> 2, kc = (ch & 3) * 8;
        *(f16x8*)&B_sh[cidx * 40 + kc] =
            *(const f16x8*)&WreT[(col0 + cidx) * KXP + kk + kc];
      }
      __syncthreads();
      f16x8 af = *(const f16x8*)&A_sh[(16 * wid + l15) * 328 + kk + q * 8];
#pragma unroll
      for (int t = 0; t < 8; ++t) {
        f16x8 bfr = *(const f16x8*)&B_sh[(t * 16 + l15) * 40 + q * 8];
        acc[t] = __builtin_amdgcn_mfma_f32_16x16x32_f16(af, bfr, acc[t], 0, 0, 0);
      }
      __syncthreads();
    }
#pragma unroll
    for (int t = 0; t < 8; ++t) {
      int col = col0 + t * 16 + l15;
      float bias = bre[col];
#pragma unroll
      for (int r2 = 0; r2 < 4; ++r2) {
        int row = row0 + 16 * wid + q * 4 + r2;
        if (row < NVOCAB) P[(long)row * NCOL + col] = (f16_t)(acc[t][r2] + bias);
      }
    }
  }
}

// Vocab-space leaf h/c tables: Hleaf[v][j], Cleaf[v][j] (f16).
__global__ void leafhc_kernel(const f16_t* __restrict__ P, f16_t* __restrict__ Hleaf,
                              f16_t* __restrict__ Cleaf) {
  int idx = blockIdx.x * 256 + threadIdx.x;
  if (idx >= NVOCAB * 80) return;
  int v = idx / 80, t = idx % 80;
  f16x8 pk = *(const f16x8*)&P[(long)v * NCOL + t * 8];
#pragma unroll
  for (int e = 0; e < 2; ++e) {
    float iv = (float)pk[e * 4 + 0], ov = (float)pk[e * 4 + 1], uv = (float)pk[e * 4 + 2];
    float cl = sigf(iv) * tanhf_(uv);
    float hl = sigf(ov) * tanhf_(cl);
    Hleaf[(long)v * HP + t * 2 + e] = (f16_t)hl;   // pads (t>=75) stay exactly 0
    Cleaf[(long)v * HP + t * 2 + e] = (f16_t)cl;
  }
}

// Oleaf[v] = Hleaf[v] @ W_out + b_out (row stride 8 floats for alignment).
__global__ void oleaf_kernel(const f16_t* __restrict__ Hleaf, const float* __restrict__ W_out,
                             const float* __restrict__ b_out, float* __restrict__ Oleaf) {
  const int tid = threadIdx.x;
  const int row = blockIdx.x * 16 + (tid >> 4), l = tid & 15;
  if (row >= NVOCAB) return;
  float acc[5] = {0, 0, 0, 0, 0};
  for (int j = l; j < 150; j += 16) {
    float hv = (float)Hleaf[(long)row * HP + j];
#pragma unroll
    for (int m = 0; m < 5; ++m) acc[m] += hv * W_out[j * 5 + m];
  }
#pragma unroll
  for (int m = 0; m < 5; ++m) {
    float vv = acc[m];
    vv += __shfl_xor(vv, 1);
    vv += __shfl_xor(vv, 2);
    vv += __shfl_xor(vv, 4);
    vv += __shfl_xor(vv, 8);
    if (l == 0) Oleaf[(long)row * 8 + m] = vv + b_out[m];
  }
}

// Leaf output rows: pure 20B gather from Oleaf.
__global__ void leafout_kernel(const int* __restrict__ x_id, const float* __restrict__ Oleaf,
                               float* __restrict__ out) {
  int leaf = blockIdx.x * 256 + threadIdx.x;
  int xv = x_id[LEAF_S + leaf];
  const float* O = Oleaf + (long)xv * 8;
  float4 o4 = *(const float4*)O;
  float o5 = O[4];
  long base = ((long)LEAF_S + leaf) * 5;
  out[base + 0] = o4.x; out[base + 1] = o4.y; out[base + 2] = o4.z;
  out[base + 3] = o4.w; out[base + 4] = o5;
}

// ---- full-K level tile: 64 children -> 32 parents, 5 stage-phases total ----
// Per jt: stage B = 128 cols x full K=160 (40 KB) in ONE phase, then 5 kk
// MFMA steps barrier-free (40 MFMA + 45 ds_read per wave per phase).
// 2 barriers/jt => 10 per pass (vs 50 in the old 25-phase structure).
template <bool LEAF>
__device__ __forceinline__ void level_tile_fk(
    const int* __restrict__ x_id, const f16_t* __restrict__ P,
    const f16_t* __restrict__ UreT, const f16_t* __restrict__ Hc,
    const f16_t* __restrict__ Cc, f16_t* __restrict__ Hp, f16_t* __restrict__ Cp,
    const float* __restrict__ W_out, const float* __restrict__ b_out,
    float* __restrict__ out, int s, int M, int p0, f16_t* A_sh, f16_t* B_sh) {
  const int tid = threadIdx.x;
  const int wid = tid >> 6, lane = tid & 63, l15 = lane & 15, q = lane >> 4;
  const long childbase = 2L * s + 1 + 2 * p0;   // node id of first child (LEAF)
  int rowsValid = 2 * M - 2 * p0;
  if (rowsValid > 64) rowsValid = 64;

  // ---- stage A: 64 child h rows (no barrier here; first B barrier covers it)
#pragma unroll
  for (int i = 0; i < 5; ++i) {
    int ch = tid + 256 * i;
    int r = ch / 20, kc = (ch % 20) * 8;
    f16x8 v;
    if (LEAF) {
      int xv = x_id[childbase + r];
      v = *(const f16x8*)&Hc[(long)xv * HP + kc];
    } else {
      v = (r < rowsValid) ? *(const f16x8*)&Hc[(long)(2 * p0 + r) * HP + kc] : zero8();
    }
    *(f16x8*)&A_sh[r * AST + kc] = v;
  }

  int xvp[2], xvl[2], xvr[2]; bool valid[2];
#pragma unroll
  for (int rr = 0; rr < 2; ++rr) {
    int pl = 8 * wid + 2 * q + rr;
    valid[rr] = (p0 + pl) < M;
    long pn = (long)s + p0 + (valid[rr] ? pl : 0);
    xvp[rr] = x_id[pn];
    if (LEAF) {
      xvl[rr] = x_id[childbase + 2 * pl];
      xvr[rr] = x_id[childbase + 2 * pl + 1];
    }
  }
  float oacc[2][5] = {};

  for (int jt = 0; jt < 5; ++jt) {
    const int j0 = jt * 32;
    // ---- stage B: full K for 128 cols (4 gates x 32 j), one phase ----
#pragma unroll
    for (int i = 0; i < 10; ++i) {
      int ch = tid + 256 * i;
      int r = ch / 20, kc = (ch % 20) * 8;
      int col = (r >> 5) * HP + j0 + (r & 31);
      *(f16x8*)&B_sh[r * AST + kc] = *(const f16x8*)&UreT[(long)col * HP + kc];
    }
    __syncthreads();

    f32x4 acc[4][2];
#pragma unroll
    for (int g = 0; g < 4; ++g)
#pragma unroll
      for (int jh = 0; jh < 2; ++jh) acc[g][jh] = zero4();

#pragma unroll
    for (int kk = 0; kk < HP; kk += 32) {
      f16x8 af = *(const f16x8*)&A_sh[(16 * wid + l15) * AST + kk + q * 8];
#pragma unroll
      for (int g = 0; g < 4; ++g)
#pragma unroll
        for (int jh = 0; jh < 2; ++jh) {
          f16x8 bfr = *(const f16x8*)&B_sh[(g * 32 + jh * 16 + l15) * AST + kk + q * 8];
          acc[g][jh] = __builtin_amdgcn_mfma_f32_16x16x32_f16(af, bfr, acc[g][jh], 0, 0, 0);
        }
    }
    __syncthreads();   // all B_sh reads done before next jt restage

    // ---- epilogue for jt (global reads/writes only; no LDS) ----
#pragma unroll
    for (int rr = 0; rr < 2; ++rr) {
      const int r = rr * 2;
      const int lr0 = 16 * wid + q * 4 + r;   // even child row
      const int pl = lr0 >> 1;                // local parent 0..31
      const f16_t* Prp = P + (long)xvp[rr] * NCOL;
#pragma unroll
      for (int jh = 0; jh < 2; ++jh) {
        const int j = j0 + jh * 16 + l15;
        f16x4 pp = *(const f16x4*)&Prp[j * 4];
        float ipre = (float)pp[0] + acc[0][jh][r] + acc[0][jh][r + 1];
        float opre = (float)pp[1] + acc[1][jh][r] + acc[1][jh][r + 1];
        float upre = (float)pp[2] + acc[2][jh][r] + acc[2][jh][r + 1];
        float pf   = (float)pp[3];
        float fl = sigf(pf + acc[3][jh][r]);
        float fr = sigf(pf + acc[3][jh][r + 1]);
        float clv, crv;
        if (LEAF) {
          clv = (float)Cc[(long)xvl[rr] * HP + j];
          crv = (float)Cc[(long)xvr[rr] * HP + j];
        } else {
          clv = valid[rr] ? (float)Cc[(long)(2 * p0 + lr0) * HP + j] : 0.0f;
          crv = valid[rr] ? (float)Cc[(long)(2 * p0 + lr0 + 1) * HP + j] : 0.0f;
        }
        float cn = sigf(ipre) * tanhf_(upre) + fl * clv + fr * crv;
        float hn = sigf(opre) * tanhf_(cn);
        if (valid[rr]) {
          Hp[(long)(p0 + pl) * HP + j] = (f16_t)hn;   // pads stay exactly 0
          Cp[(long)(p0 + pl) * HP + j] = (f16_t)cn;
        }
        int wbase = (j < 150) ? j * 5 : 0;            // hn==0 on pads
#pragma unroll
        for (int m = 0; m < 5; ++m) oacc[rr][m] += hn * W_out[wbase + m];
      }
    }
  }

#pragma unroll
  for (int rr = 0; rr < 2; ++rr) {
    int pl = 8 * wid + 2 * q + rr;
#pragma unroll
    for (int m = 0; m < 5; ++m) {
      float v = oacc[rr][m];
      v += __shfl_xor(v, 1);
      v += __shfl_xor(v, 2);
      v += __shfl_xor(v, 4);
      v += __shfl_xor(v, 8);
      if (l15 == 0 && valid[rr]) out[((long)s + p0 + pl) * 5 + m] = v + b_out[m];
    }
  }
}

// Single level, full-K staging. LDS 64.5 KB -> 2 blocks/CU.
template <bool LEAF>
__global__ __launch_bounds__(256, 2) void level_kernel(
    const int* __restrict__ x_id, const f16_t* __restrict__ P,
    const f16_t* __restrict__ UreT, const f16_t* __restrict__ Hc,
    const f16_t* __restrict__ Cc, f16_t* __restrict__ Hout,
    f16_t* __restrict__ Cout, const float* __restrict__ W_out,
    const float* __restrict__ b_out, float* __restrict__ out, int s, int M) {
  __shared__ __align__(16) f16_t A_sh[64 * AST];
  __shared__ __align__(16) f16_t B_sh[128 * AST];
  level_tile_fk<LEAF>(x_id, P, UreT, Hc, Cc, Hout, Cout, W_out, b_out, out,
                      s, M, blockIdx.x * 32, A_sh, B_sh);
}

// Two fused levels per block (round-3 proven structure) — kept for (16,15)
// where single-level outputs (42 MB x2) would not fit the workspace.
template <bool LEAF>
__global__ __launch_bounds__(256, 3) void fused_kernel(
    const int* __restrict__ x_id, const f16_t* __restrict__ P,
    const f16_t* __restrict__ UreT, const f16_t* __restrict__ Hc,
    const f16_t* __restrict__ Cc, f16_t* __restrict__ Hout,
    f16_t* __restrict__ Cout, const float* __restrict__ W_out,
    const float* __restrict__ b_out, float* __restrict__ out, int s1, int M1) {
  __shared__ __align__(16) f16_t A_sh[64 * AST];
  __shared__ __align__(16) f16_t A2_sh[32 * AST];
  __shared__ __align__(16) f16_t B_sh[128 * 40];
  __shared__ f16_t C_sh[32 * 160];
  const int tid = threadIdx.x;
  const int wid = tid >> 6, lane = tid & 63, l15 = lane & 15, q = lane >> 4;
  const int p0 = blockIdx.x * 32;
  const long childbase = 2L * s1 + 1 + 2 * p0;

#pragma unroll
  for (int i = 0; i < 5; ++i) {
    int ch = tid + 256 * i;
    int r = ch / 20, kc = (ch % 20) * 8;
    f16x8 v;
    if (LEAF) {
      int xv = x_id[childbase + r];
      v = *(const f16x8*)&Hc[(long)xv * HP + kc];
    } else {
      v = *(const f16x8*)&Hc[(long)(2 * p0 + r) * HP + kc];
    }
    *(f16x8*)&A_sh[r * AST + kc] = v;
  }
  __syncthreads();

  int xvp[2], xvl[2], xvr[2];
#pragma unroll
  for (int rr = 0; rr < 2; ++rr) {
    int pl = 8 * wid + 2 * q + rr;
    long pn = (long)s1 + p0 + pl;
    xvp[rr] = x_id[pn];
    if (LEAF) {
      xvl[rr] = x_id[childbase + 2 * pl];
      xvr[rr] = x_id[childbase + 2 * pl + 1];
    }
  }
  float oacc1[2][5] = {};

  for (int jt = 0; jt < 5; ++jt) {
    const int j0 = jt * 32;
    f32x4 acc[4][2];
#pragma unroll
    for (int g = 0; g < 4; ++g)
#pragma unroll
      for (int jh = 0; jh < 2; ++jh) acc[g][jh] = zero4();

    for (int kk = 0; kk < HP; kk += 32) {
#pragma unroll
      for (int i = 0; i < 2; ++i) {
        int ch = tid + 256 * i;
        int cidx = ch >> 2, kc = (ch & 3) * 8;
        int g = cidx >> 5, jj = cidx & 31;
        int col = g * HP + j0 + jj;
        *(f16x8*)&B_sh[cidx * 40 + kc] = *(const f16x8*)&UreT[col * HP + kk + kc];
      }
      __syncthreads();
      f16x8 af = *(const f16x8*)&A_sh[(16 * wid + l15) * AST + kk + q * 8];
#pragma unroll
      for (int g = 0; g < 4; ++g)
#pragma unroll
        for (int jh = 0; jh < 2; ++jh) {
          f16x8 bfr = *(const f16x8*)&B_sh[(g * 32 + jh * 16 + l15) * 40 + q * 8];
          acc[g][jh] = __builtin_amdgcn_mfma_f32_16x16x32_f16(af, bfr, acc[g][jh], 0, 0, 0);
        }
      __syncthreads();
    }

#pragma unroll
    for (int rr = 0; rr < 2; ++rr) {
      const int r = rr * 2;
      const int lr0 = 16 * wid + q * 4 + r;
      const int pl = lr0 >> 1;
      const f16_t* Prp = P + (long)xvp[rr] * NCOL;
#pragma unroll
      for (int jh = 0; jh < 2; ++jh) {
        const int j = j0 + jh * 16 + l15;
        f16x4 pp = *(const f16x4*)&Prp[j * 4];
        float ipre = (float)pp[0] + acc[0][jh][r] + acc[0][jh][r + 1];
        float opre = (float)pp[1] + acc[1][jh][r] + acc[1][jh][r + 1];
        float upre = (float)pp[2] + acc[2][jh][r] + acc[2][jh][r + 1];
        float pf   = (float)pp[3];
        float fl = sigf(pf + acc[3][jh][r]);
        float fr = sigf(pf + acc[3][jh][r + 1]);
        float clv, crv;
        if (LEAF) {
          clv = (float)Cc[(long)xvl[rr] * HP + j];
          crv = (float)Cc[(long)xvr[rr] * HP + j];
        } else {
          clv = (float)Cc[(long)(2 * p0 + lr0) * HP + j];
          crv = (float)Cc[(long)(2 * p0 + lr0 + 1) * HP + j];
        }
        float cn = sigf(ipre) * tanhf_(upre) + fl * clv + fr * crv;
        float hn = sigf(opre) * tanhf_(cn);
        A2_sh[pl * AST + j] = (f16_t)hn;
        C_sh[pl * 160 + j] = (f16_t)cn;
        int wbase = (j < 150) ? j * 5 : 0;
#pragma unroll
        for (int m = 0; m < 5; ++m) oacc1[rr][m] += hn * W_out[wbase + m];
      }
    }
  }

#pragma unroll
  for (int rr = 0; rr < 2; ++rr) {
    int pl = 8 * wid + 2 * q + rr;
#pragma unroll
    for (int m = 0; m < 5; ++m) {
      float v = oacc1[rr][m];
      v += __shfl_xor(v, 1);
      v += __shfl_xor(v, 2);
      v += __shfl_xor(v, 4);
      v += __shfl_xor(v, 8);
      if (l15 == 0) out[((long)s1 + p0 + pl) * 5 + m] = v + b_out[m];
    }
  }

  const int s2 = (s1 - 1) >> 1;
  const int p02 = p0 >> 1;
  const bool act2 = (wid < 2);
  int xvp2[2];
#pragma unroll
  for (int rr = 0; rr < 2; ++rr) {
    int pl = 8 * wid + 2 * q + rr;
    long pn = (long)s2 + p02 + (act2 ? pl : 0);
    xvp2[rr] = x_id[pn];
  }
  float oacc2[2][5] = {};

  for (int jt = 0; jt < 5; ++jt) {
    const int j0 = jt * 32;
    f32x4 acc[4][2];
#pragma unroll
    for (int g = 0; g < 4; ++g)
#pragma unroll
      for (int jh = 0; jh < 2; ++jh) acc[g][jh] = zero4();

    for (int kk = 0; kk < HP; kk += 32) {
#pragma unroll
      for (int i = 0; i < 2; ++i) {
        int ch = tid + 256 * i;
        int cidx = ch >> 2, kc = (ch & 3) * 8;
        int g = cidx >> 5, jj = cidx & 31;
        int col = g * HP + j0 + jj;
        *(f16x8*)&B_sh[cidx * 40 + kc] = *(const f16x8*)&UreT[col * HP + kk + kc];
      }
      __syncthreads();
      if (act2) {
        f16x8 af = *(const f16x8*)&A2_sh[(16 * wid + l15) * AST + kk + q * 8];
#pragma unroll
        for (int g = 0; g < 4; ++g)
#pragma unroll
          for (int jh = 0; jh < 2; ++jh) {
            f16x8 bfr = *(const f16x8*)&B_sh[(g * 32 + jh * 16 + l15) * 40 + q * 8];
            acc[g][jh] = __builtin_amdgcn_mfma_f32_16x16x32_f16(af, bfr, acc[g][jh], 0, 0, 0);
          }
      }
      __syncthreads();
    }

    if (act2) {
#pragma unroll
      for (int rr = 0; rr < 2; ++rr) {
        const int r = rr * 2;
        const int lr0 = 16 * wid + q * 4 + r;
        const int pl = lr0 >> 1;
        const f16_t* Prp = P + (long)xvp2[rr] * NCOL;
#pragma unroll
        for (int jh = 0; jh < 2; ++jh) {
          const int j = j0 + jh * 16 + l15;
          f16x4 pp = *(const f16x4*)&Prp[j * 4];
          float ipre = (float)pp[0] + acc[0][jh][r] + acc[0][jh][r + 1];
          float opre = (float)pp[1] + acc[1][jh][r] + acc[1][jh][r + 1];
          float upre = (float)pp[2] + acc[2][jh][r] + acc[2][jh][r + 1];
          float pf   = (float)pp[3];
          float fl = sigf(pf + acc[3][jh][r]);
          float fr = sigf(pf + acc[3][jh][r + 1]);
          float clv = (float)C_sh[lr0 * 160 + j];
          float crv = (float)C_sh[(lr0 + 1) * 160 + j];
          float cn = sigf(ipre) * tanhf_(upre) + fl * clv + fr * crv;
          float hn = sigf(opre) * tanhf_(cn);
          Hout[(long)(p02 + pl) * HP + j] = (f16_t)hn;
          Cout[(long)(p02 + pl) * HP + j] = (f16_t)cn;
          int wbase = (j < 150) ? j * 5 : 0;
#pragma unroll
          for (int m = 0; m < 5; ++m) oacc2[rr][m] += hn * W_out[wbase + m];
        }
      }
    }
  }

  if (act2) {
#pragma unroll
    for (int rr = 0; rr < 2; ++rr) {
      int pl = 8 * wid + 2 * q + rr;
#pragma unroll
      for (int m = 0; m < 5; ++m) {
        float v = oacc2[rr][m];
        v += __shfl_xor(v, 1);
        v += __shfl_xor(v, 2);
        v += __shfl_xor(v, 4);
        v += __shfl_xor(v, 8);
        if (l15 == 0) out[((long)s2 + p02 + pl) * 5 + m] = v + b_out[m];
      }
    }
  }
}

// Levels 5..0 in one block (children: L6 rows in HB/CB), full-K phase
// structure: 6 levels x 5 phases = 30 phases (vs 125 in the old tail).
__global__ __launch_bounds__(256, 2) void tail_fk(
    const int* __restrict__ x_id, const f16_t* __restrict__ P,
    const f16_t* __restrict__ UreT, f16_t* __restrict__ HA, f16_t* __restrict__ HB,
    f16_t* __restrict__ CA, f16_t* __restrict__ CB, const float* __restrict__ W_out,
    const float* __restrict__ b_out, float* __restrict__ out) {
  __shared__ __align__(16) f16_t A_sh[64 * AST];
  __shared__ __align__(16) f16_t B_sh[128 * AST];
  for (int lvl = 5; lvl >= 0; --lvl) {
    int s = (1 << lvl) - 1, M = 1 << lvl;
    const f16_t* hc = ((lvl + 1) & 1) ? HA : HB;
    const f16_t* cc = ((lvl + 1) & 1) ? CA : CB;
    f16_t* hp = (lvl & 1) ? HA : HB;
    f16_t* cp = (lvl & 1) ? CA : CB;
    level_tile_fk<false>(x_id, P, UreT, hc, cc, hp, cp, W_out, b_out, out,
                         s, M, 0, A_sh, B_sh);
    __syncthreads();
  }
}

extern "C" void kernel_launch(void* const* d_in, const int* in_sizes, int n_in,
                              void* d_out, int out_size, void* d_ws, size_t ws_size,
                              hipStream_t stream) {
  const int* x_id   = (const int*)d_in[0];
  const float* emb  = (const float*)d_in[1];
  const float* W_iou = (const float*)d_in[2];
  const float* U_iou = (const float*)d_in[3];
  const float* b_iou = (const float*)d_in[4];
  const float* W_f   = (const float*)d_in[5];
  const float* U_f   = (const float*)d_in[6];
  const float* b_f   = (const float*)d_in[7];
  const float* W_out = (const float*)d_in[8];
  const float* b_out = (const float*)d_in[9];
  float* out = (float*)d_out;
  char* ws = (char*)d_ws;

  // workspace carve (bytes), peak 180,503,040 <= 182,103,040 budget.
  // All region reuses are stream-ordered (writer launched after last reader).
  f16_t* WreT  = (f16_t*)(ws + 0);              // 409,600
  f16_t* UreT  = (f16_t*)(ws + 409600);         // 204,800
  float* bre   = (float*)(ws + 614400);         // 2,560
  f16_t* P     = (f16_t*)(ws + 616960);         // 64,000,000 (persistent)
  f16_t* Hleaf = (f16_t*)(ws + 64616960);       // 16,000,000 (dead after L17)
  f16_t* Cleaf = (f16_t*)(ws + 80616960);       // 16,000,000 (dead after L17)
  float* Oleaf = (float*)(ws + 96616960);       // 1,600,000 (dead after leafout)
  f16_t* H17   = (f16_t*)(ws + 96616960);       // 41,943,040 (131072 rows)
  f16_t* C17   = (f16_t*)(ws + 138560000);      // 41,943,040 -> ends 180,503,040
  f16_t* H15   = (f16_t*)(ws + 64616960);       // 10,485,760 (32768 rows) over Hleaf
  f16_t* C15   = (f16_t*)(ws + 75102720);       // 10,485,760 -> ends 85,588,480
  // Single-level chain L14..L6: ping-pong regions. Even L -> region B
  // (96,616,960, over dead H17 once fused(16,15) completed); odd L -> region A
  // (85,588,480). Consecutive levels always land in different regions;
  // overwrites only hit 2-generations-old data (already consumed).
  f16_t* HL[15]; f16_t* CL[15];
  for (int L = 14; L >= 6; --L) {
    size_t rows = (size_t)1 << L;
    char* base = ((L & 1) == 0) ? (ws + 96616960) : (ws + 85588480);
    HL[L] = (f16_t*)base;
    CL[L] = (f16_t*)(base + rows * 320);
  }
  // tail scratch (32 rows): region A base (L7 data dead by tail time)
  f16_t* HT = (f16_t*)(ws + 85588480);
  f16_t* CT = (f16_t*)(ws + 85598720);

  prep_params<<<1203, 256, 0, stream>>>(W_iou, U_iou, b_iou, W_f, U_f, b_f, WreT, UreT, bre);
  gemm_p<<<782, 256, 0, stream>>>(emb, WreT, bre, P);
  leafhc_kernel<<<15625, 256, 0, stream>>>(P, Hleaf, Cleaf);
  oleaf_kernel<<<3125, 256, 0, stream>>>(Hleaf, W_out, b_out, Oleaf);
  leafout_kernel<<<1024, 256, 0, stream>>>(x_id, Oleaf, out);

  // L17 (full-K structure, leaf gather): leaves -> H17/C17
  level_kernel<true><<<4096, 256, 0, stream>>>(x_id, P, UreT, Hleaf, Cleaf,
                                               H17, C17, W_out, b_out, out,
                                               (1 << 17) - 1, 1 << 17);
  // L16+L15 fused (outputs too large for single-level workspace):
  fused_kernel<false><<<2048, 256, 0, stream>>>(x_id, P, UreT, H17, C17, H15, C15,
                                                W_out, b_out, out, (1 << 16) - 1, 1 << 16);
  // L14..L6 single levels (full-K structure):
  {
    const f16_t* hc = H15; const f16_t* cc = C15;
    for (int L = 14; L >= 6; --L) {
      int M = 1 << L;
      level_kernel<false><<<(M + 31) / 32, 256, 0, stream>>>(
          x_id, P, UreT, hc, cc, HL[L], CL[L], W_out, b_out, out, M - 1, M);
      hc = HL[L]; cc = CL[L];
    }
  }
  // L5..L0 in one block (children = L6 rows in HB/CB slots):
  tail_fk<<<1, 256, 0, stream>>>(x_id, P, UreT, HT, HL[6], CT, CL[6],
                                 W_out, b_out, out);

  (void)in_sizes; (void)n_in; (void)out_size; (void)ws_size;
}

// Round 9
// 814.531 us; speedup vs baseline: 1.2170x; 1.0858x over previous
//
#include <hip/hip_runtime.h>
#include <cstdint>

typedef _Float16 f16_t;
typedef __attribute__((ext_vector_type(8))) _Float16 f16x8;
typedef __attribute__((ext_vector_type(4))) _Float16 f16x4;
typedef __attribute__((ext_vector_type(4))) float f32x4;

#define HP      160      // padded H (150 -> 160): h/c row stride, U K-dim
#define NCOL    640      // 160 j x 4 gates (P is [v][j][g] interleaved)
#define KXP     320      // padded X_SIZE (300 -> 320)
#define NNODES  524287
#define LEAF_S  262143
#define LEAF_M  262144
#define NVOCAB  50000
#define AST     168      // A_sh stride (f16): 16B-aligned, 2-way-bank-free

__device__ __forceinline__ float frcp(float x) { return __builtin_amdgcn_rcpf(x); }
__device__ __forceinline__ float sigf(float x) { return frcp(1.0f + __expf(-x)); }
__device__ __forceinline__ float tanhf_(float x) {
  return 1.0f - 2.0f * frcp(1.0f + __expf(2.0f * x));
}
__device__ __forceinline__ f16x8 zero8() {
  f16x8 z;
#pragma unroll
  for (int i = 0; i < 8; ++i) z[i] = (_Float16)0.0f;
  return z;
}
__device__ __forceinline__ f32x4 zero4() {
  f32x4 z;
#pragma unroll
  for (int i = 0; i < 4; ++i) z[i] = 0.0f;
  return z;
}

// WreT[colIdx][k], colIdx = j*4+g (interleaved, matches P);
// UreT[col][k], col = g*160+j (g-major, matches B staging); bre interleaved.
__global__ void prep_params(const float* __restrict__ W_iou, const float* __restrict__ U_iou,
                            const float* __restrict__ b_iou, const float* __restrict__ W_f,
                            const float* __restrict__ U_f, const float* __restrict__ b_f,
                            f16_t* __restrict__ WreT, f16_t* __restrict__ UreT,
                            float* __restrict__ bre) {
  int idx = blockIdx.x * 256 + threadIdx.x;
  if (idx < NCOL * KXP) {
    int col = idx / KXP, k = idx % KXP;
    int j = col >> 2, g = col & 3;
    float v = 0.0f;
    if (k < 300 && j < 150) v = (g < 3) ? W_iou[k * 450 + g * 150 + j] : W_f[k * 150 + j];
    WreT[idx] = (f16_t)v;
  } else if (idx < NCOL * KXP + NCOL * HP) {
    int i2 = idx - NCOL * KXP;
    int col = i2 / HP, k = i2 % HP;
    int g = col / 160, j = col % 160;
    float v = 0.0f;
    if (k < 150 && j < 150) v = (g < 3) ? U_iou[k * 450 + g * 150 + j] : U_f[k * 150 + j];
    UreT[i2] = (f16_t)v;
  } else if (idx < NCOL * KXP + NCOL * HP + NCOL) {
    int col = idx - (NCOL * KXP + NCOL * HP);
    int j = col >> 2, g = col & 3;
    bre[col] = (j < 150) ? ((g < 3) ? b_iou[g * 150 + j] : b_f[j]) : 0.0f;
  }
}

// P[v][j][g] = emb @ W + b, fp16, 50000 x 640 (interleaved cols).
__global__ __launch_bounds__(256) void gemm_p(const float* __restrict__ emb,
                                              const f16_t* __restrict__ WreT,
                                              const float* __restrict__ bre,
                                              f16_t* __restrict__ P) {
  __shared__ __align__(16) f16_t A_sh[64 * 328];
  __shared__ __align__(16) f16_t B_sh[128 * 40];
  const int tid = threadIdx.x;
  const int wid = tid >> 6, lane = tid & 63, l15 = lane & 15, q = lane >> 4;
  const int row0 = blockIdx.x * 64;

#pragma unroll
  for (int i = 0; i < 10; ++i) {
    int ch = tid + 256 * i;
    int r = ch / 40, kc = (ch % 40) * 8;
    int grow = row0 + r;
    f16x8 hv;
    if (grow < NVOCAB && kc + 8 <= 300) {
      float4 a = *(const float4*)&emb[grow * 300 + kc];
      float4 b = *(const float4*)&emb[grow * 300 + kc + 4];
      hv[0] = (_Float16)a.x; hv[1] = (_Float16)a.y; hv[2] = (_Float16)a.z; hv[3] = (_Float16)a.w;
      hv[4] = (_Float16)b.x; hv[5] = (_Float16)b.y; hv[6] = (_Float16)b.z; hv[7] = (_Float16)b.w;
    } else {
#pragma unroll
      for (int e = 0; e < 8; ++e) {
        int k = kc + e;
        float v = (grow < NVOCAB && k < 300) ? emb[grow * 300 + k] : 0.0f;
        hv[e] = (_Float16)v;
      }
    }
    *(f16x8*)&A_sh[r * 328 + kc] = hv;
  }
  __syncthreads();

  for (int bn = 0; bn < 5; ++bn) {
    const int col0 = bn * 128;
    f32x4 acc[8];
#pragma unroll
    for (int t = 0; t < 8; ++t) acc[t] = zero4();
    for (int kk = 0; kk < KXP; kk += 32) {
#pragma unroll
      for (int i = 0; i < 2; ++i) {
        int ch = tid + 256 * i;
        int cidx = ch >> 2, kc = (ch & 3) * 8;
        *(f16x8*)&B_sh[cidx * 40 + kc] =
            *(const f16x8*)&WreT[(col0 + cidx) * KXP + kk + kc];
      }
      __syncthreads();
      f16x8 af = *(const f16x8*)&A_sh[(16 * wid + l15) * 328 + kk + q * 8];
#pragma unroll
      for (int t = 0; t < 8; ++t) {
        f16x8 bfr = *(const f16x8*)&B_sh[(t * 16 + l15) * 40 + q * 8];
        acc[t] = __builtin_amdgcn_mfma_f32_16x16x32_f16(af, bfr, acc[t], 0, 0, 0);
      }
      __syncthreads();
    }
#pragma unroll
    for (int t = 0; t < 8; ++t) {
      int col = col0 + t * 16 + l15;
      float bias = bre[col];
#pragma unroll
      for (int r2 = 0; r2 < 4; ++r2) {
        int row = row0 + 16 * wid + q * 4 + r2;
        if (row < NVOCAB) P[(long)row * NCOL + col] = (f16_t)(acc[t][r2] + bias);
      }
    }
  }
}

// Vocab-space leaf h/c tables: Hleaf[v][j], Cleaf[v][j] (f16).
__global__ void leafhc_kernel(const f16_t* __restrict__ P, f16_t* __restrict__ Hleaf,
                              f16_t* __restrict__ Cleaf) {
  int idx = blockIdx.x * 256 + threadIdx.x;
  if (idx >= NVOCAB * 80) return;
  int v = idx / 80, t = idx % 80;
  f16x8 pk = *(const f16x8*)&P[(long)v * NCOL + t * 8];
#pragma unroll
  for (int e = 0; e < 2; ++e) {
    float iv = (float)pk[e * 4 + 0], ov = (float)pk[e * 4 + 1], uv = (float)pk[e * 4 + 2];
    float cl = sigf(iv) * tanhf_(uv);
    float hl = sigf(ov) * tanhf_(cl);
    Hleaf[(long)v * HP + t * 2 + e] = (f16_t)hl;   // pads (t>=75) stay exactly 0
    Cleaf[(long)v * HP + t * 2 + e] = (f16_t)cl;
  }
}

// Oleaf[v] = Hleaf[v] @ W_out + b_out (row stride 8 floats for alignment).
__global__ void oleaf_kernel(const f16_t* __restrict__ Hleaf, const float* __restrict__ W_out,
                             const float* __restrict__ b_out, float* __restrict__ Oleaf) {
  const int tid = threadIdx.x;
  const int row = blockIdx.x * 16 + (tid >> 4), l = tid & 15;
  if (row >= NVOCAB) return;
  float acc[5] = {0, 0, 0, 0, 0};
  for (int j = l; j < 150; j += 16) {
    float hv = (float)Hleaf[(long)row * HP + j];
#pragma unroll
    for (int m = 0; m < 5; ++m) acc[m] += hv * W_out[j * 5 + m];
  }
#pragma unroll
  for (int m = 0; m < 5; ++m) {
    float vv = acc[m];
    vv += __shfl_xor(vv, 1);
    vv += __shfl_xor(vv, 2);
    vv += __shfl_xor(vv, 4);
    vv += __shfl_xor(vv, 8);
    if (l == 0) Oleaf[(long)row * 8 + m] = vv + b_out[m];
  }
}

// Leaf output rows: pure 20B gather from Oleaf.
__global__ void leafout_kernel(const int* __restrict__ x_id, const float* __restrict__ Oleaf,
                               float* __restrict__ out) {
  int leaf = blockIdx.x * 256 + threadIdx.x;
  int xv = x_id[LEAF_S + leaf];
  const float* O = Oleaf + (long)xv * 8;
  float4 o4 = *(const float4*)O;
  float o5 = O[4];
  long base = ((long)LEAF_S + leaf) * 5;
  out[base + 0] = o4.x; out[base + 1] = o4.y; out[base + 2] = o4.z;
  out[base + 3] = o4.w; out[base + 4] = o5;
}

// LEVEL 17, big-M tile: 128 leaves -> 64 parents per block (2048 blocks).
// A_sh = 128 rows (43 KB), B staging unchanged (10 KB/phase) => staging per
// parent HALVED vs the 64-child version. Each wave owns two 16-row m-tiles
// (af0/af1), 16 MFMA per phase. LDS 53.2 KB -> 3 blocks/CU.
__global__ __launch_bounds__(256, 3) void level17b_kernel(
    const int* __restrict__ x_id, const f16_t* __restrict__ P,
    const f16_t* __restrict__ UreT, const f16_t* __restrict__ Hleaf,
    const f16_t* __restrict__ Cleaf, f16_t* __restrict__ Hout,
    f16_t* __restrict__ Cout, const float* __restrict__ W_out,
    const float* __restrict__ b_out, float* __restrict__ out) {
  __shared__ __align__(16) f16_t A_sh[128 * AST];
  __shared__ __align__(16) f16_t B_sh[128 * 40];
  const int tid = threadIdx.x;
  const int wid = tid >> 6, lane = tid & 63, l15 = lane & 15, q = lane >> 4;
  const int p0 = blockIdx.x * 64;
  const int s1 = (1 << 17) - 1;                  // 131071
  const long childbase = 2L * s1 + 1 + 2 * p0;   // first child (leaf) node id

  // ---- stage A: 128 child h rows (x_id gather from vocab table) ----
#pragma unroll
  for (int i = 0; i < 10; ++i) {
    int ch = tid + 256 * i;
    int r = ch / 20, kc = (ch % 20) * 8;
    int xv = x_id[childbase + r];
    *(f16x8*)&A_sh[r * AST + kc] = *(const f16x8*)&Hleaf[(long)xv * HP + kc];
  }
  __syncthreads();

  int xvp[2][2], xvl[2][2], xvr[2][2];
#pragma unroll
  for (int mt = 0; mt < 2; ++mt)
#pragma unroll
    for (int rr = 0; rr < 2; ++rr) {
      int pl = 16 * wid + 8 * mt + 2 * q + rr;   // 0..63
      xvp[mt][rr] = x_id[(long)s1 + p0 + pl];
      xvl[mt][rr] = x_id[childbase + 2 * pl];
      xvr[mt][rr] = x_id[childbase + 2 * pl + 1];
    }
  float oacc[2][2][5] = {};

  for (int jt = 0; jt < 5; ++jt) {
    const int j0 = jt * 32;
    f32x4 acc[2][4][2];
#pragma unroll
    for (int mt = 0; mt < 2; ++mt)
#pragma unroll
      for (int g = 0; g < 4; ++g)
#pragma unroll
        for (int jh = 0; jh < 2; ++jh) acc[mt][g][jh] = zero4();

    for (int kk = 0; kk < HP; kk += 32) {
#pragma unroll
      for (int i = 0; i < 2; ++i) {
        int ch = tid + 256 * i;
        int cidx = ch >> 2, kc = (ch & 3) * 8;
        int g = cidx >> 5, jj = cidx & 31;
        int col = g * HP + j0 + jj;
        *(f16x8*)&B_sh[cidx * 40 + kc] = *(const f16x8*)&UreT[col * HP + kk + kc];
      }
      __syncthreads();
      f16x8 af0 = *(const f16x8*)&A_sh[(32 * wid + l15) * AST + kk + q * 8];
      f16x8 af1 = *(const f16x8*)&A_sh[(32 * wid + 16 + l15) * AST + kk + q * 8];
#pragma unroll
      for (int g = 0; g < 4; ++g)
#pragma unroll
        for (int jh = 0; jh < 2; ++jh) {
          f16x8 bfr = *(const f16x8*)&B_sh[(g * 32 + jh * 16 + l15) * 40 + q * 8];
          acc[0][g][jh] = __builtin_amdgcn_mfma_f32_16x16x32_f16(af0, bfr, acc[0][g][jh], 0, 0, 0);
          acc[1][g][jh] = __builtin_amdgcn_mfma_f32_16x16x32_f16(af1, bfr, acc[1][g][jh], 0, 0, 0);
        }
      __syncthreads();
    }

#pragma unroll
    for (int mt = 0; mt < 2; ++mt)
#pragma unroll
      for (int rr = 0; rr < 2; ++rr) {
        const int r = rr * 2;
        const int pl = 16 * wid + 8 * mt + 2 * q + rr;  // local parent 0..63
        const f16_t* Prp = P + (long)xvp[mt][rr] * NCOL;
#pragma unroll
        for (int jh = 0; jh < 2; ++jh) {
          const int j = j0 + jh * 16 + l15;
          f16x4 pp = *(const f16x4*)&Prp[j * 4];
          float ipre = (float)pp[0] + acc[mt][0][jh][r] + acc[mt][0][jh][r + 1];
          float opre = (float)pp[1] + acc[mt][1][jh][r] + acc[mt][1][jh][r + 1];
          float upre = (float)pp[2] + acc[mt][2][jh][r] + acc[mt][2][jh][r + 1];
          float pf   = (float)pp[3];
          float fl = sigf(pf + acc[mt][3][jh][r]);
          float fr = sigf(pf + acc[mt][3][jh][r + 1]);
          float clv = (float)Cleaf[(long)xvl[mt][rr] * HP + j];
          float crv = (float)Cleaf[(long)xvr[mt][rr] * HP + j];
          float cn = sigf(ipre) * tanhf_(upre) + fl * clv + fr * crv;
          float hn = sigf(opre) * tanhf_(cn);
          Hout[(long)(p0 + pl) * HP + j] = (f16_t)hn;   // pads stay exactly 0
          Cout[(long)(p0 + pl) * HP + j] = (f16_t)cn;
          int wbase = (j < 150) ? j * 5 : 0;            // hn==0 on pads
#pragma unroll
          for (int m = 0; m < 5; ++m) oacc[mt][rr][m] += hn * W_out[wbase + m];
        }
      }
  }

#pragma unroll
  for (int mt = 0; mt < 2; ++mt)
#pragma unroll
    for (int rr = 0; rr < 2; ++rr) {
      int pl = 16 * wid + 8 * mt + 2 * q + rr;
#pragma unroll
      for (int m = 0; m < 5; ++m) {
        float v = oacc[mt][rr][m];
        v += __shfl_xor(v, 1);
        v += __shfl_xor(v, 2);
        v += __shfl_xor(v, 4);
        v += __shfl_xor(v, 8);
        if (l15 == 0) out[((long)s1 + p0 + pl) * 5 + m] = v + b_out[m];
      }
    }
}

// Two fused levels per block (round-0/3 proven structure): 64 children -> 32
// parents (level s1) -> 16 grandparents. Pass-1 parent h -> A2_sh, c -> C_sh.
template <bool LEAF>
__global__ __launch_bounds__(256, 3) void fused_kernel(
    const int* __restrict__ x_id, const f16_t* __restrict__ P,
    const f16_t* __restrict__ UreT, const f16_t* __restrict__ Hc,
    const f16_t* __restrict__ Cc, f16_t* __restrict__ Hout,
    f16_t* __restrict__ Cout, const float* __restrict__ W_out,
    const float* __restrict__ b_out, float* __restrict__ out, int s1, int M1) {
  __shared__ __align__(16) f16_t A_sh[64 * AST];
  __shared__ __align__(16) f16_t A2_sh[32 * AST];
  __shared__ __align__(16) f16_t B_sh[128 * 40];
  __shared__ f16_t C_sh[32 * 160];
  const int tid = threadIdx.x;
  const int wid = tid >> 6, lane = tid & 63, l15 = lane & 15, q = lane >> 4;
  const int p0 = blockIdx.x * 32;
  const long childbase = 2L * s1 + 1 + 2 * p0;

#pragma unroll
  for (int i = 0; i < 5; ++i) {
    int ch = tid + 256 * i;
    int r = ch / 20, kc = (ch % 20) * 8;
    f16x8 v;
    if (LEAF) {
      int xv = x_id[childbase + r];
      v = *(const f16x8*)&Hc[(long)xv * HP + kc];
    } else {
      v = *(const f16x8*)&Hc[(long)(2 * p0 + r) * HP + kc];
    }
    *(f16x8*)&A_sh[r * AST + kc] = v;
  }
  __syncthreads();

  int xvp[2], xvl[2], xvr[2];
#pragma unroll
  for (int rr = 0; rr < 2; ++rr) {
    int pl = 8 * wid + 2 * q + rr;
    long pn = (long)s1 + p0 + pl;
    xvp[rr] = x_id[pn];
    if (LEAF) {
      xvl[rr] = x_id[childbase + 2 * pl];
      xvr[rr] = x_id[childbase + 2 * pl + 1];
    }
  }
  float oacc1[2][5] = {};

  for (int jt = 0; jt < 5; ++jt) {
    const int j0 = jt * 32;
    f32x4 acc[4][2];
#pragma unroll
    for (int g = 0; g < 4; ++g)
#pragma unroll
      for (int jh = 0; jh < 2; ++jh) acc[g][jh] = zero4();

    for (int kk = 0; kk < HP; kk += 32) {
#pragma unroll
      for (int i = 0; i < 2; ++i) {
        int ch = tid + 256 * i;
        int cidx = ch >> 2, kc = (ch & 3) * 8;
        int g = cidx >> 5, jj = cidx & 31;
        int col = g * HP + j0 + jj;
        *(f16x8*)&B_sh[cidx * 40 + kc] = *(const f16x8*)&UreT[col * HP + kk + kc];
      }
      __syncthreads();
      f16x8 af = *(const f16x8*)&A_sh[(16 * wid + l15) * AST + kk + q * 8];
#pragma unroll
      for (int g = 0; g < 4; ++g)
#pragma unroll
        for (int jh = 0; jh < 2; ++jh) {
          f16x8 bfr = *(const f16x8*)&B_sh[(g * 32 + jh * 16 + l15) * 40 + q * 8];
          acc[g][jh] = __builtin_amdgcn_mfma_f32_16x16x32_f16(af, bfr, acc[g][jh], 0, 0, 0);
        }
      __syncthreads();
    }

#pragma unroll
    for (int rr = 0; rr < 2; ++rr) {
      const int r = rr * 2;
      const int lr0 = 16 * wid + q * 4 + r;
      const int pl = lr0 >> 1;
      const f16_t* Prp = P + (long)xvp[rr] * NCOL;
#pragma unroll
      for (int jh = 0; jh < 2; ++jh) {
        const int j = j0 + jh * 16 + l15;
        f16x4 pp = *(const f16x4*)&Prp[j * 4];
        float ipre = (float)pp[0] + acc[0][jh][r] + acc[0][jh][r + 1];
        float opre = (float)pp[1] + acc[1][jh][r] + acc[1][jh][r + 1];
        float upre = (float)pp[2] + acc[2][jh][r] + acc[2][jh][r + 1];
        float pf   = (float)pp[3];
        float fl = sigf(pf + acc[3][jh][r]);
        float fr = sigf(pf + acc[3][jh][r + 1]);
        float clv, crv;
        if (LEAF) {
          clv = (float)Cc[(long)xvl[rr] * HP + j];
          crv = (float)Cc[(long)xvr[rr] * HP + j];
        } else {
          clv = (float)Cc[(long)(2 * p0 + lr0) * HP + j];
          crv = (float)Cc[(long)(2 * p0 + lr0 + 1) * HP + j];
        }
        float cn = sigf(ipre) * tanhf_(upre) + fl * clv + fr * crv;
        float hn = sigf(opre) * tanhf_(cn);
        A2_sh[pl * AST + j] = (f16_t)hn;
        C_sh[pl * 160 + j] = (f16_t)cn;
        int wbase = (j < 150) ? j * 5 : 0;
#pragma unroll
        for (int m = 0; m < 5; ++m) oacc1[rr][m] += hn * W_out[wbase + m];
      }
    }
  }

#pragma unroll
  for (int rr = 0; rr < 2; ++rr) {
    int pl = 8 * wid + 2 * q + rr;
#pragma unroll
    for (int m = 0; m < 5; ++m) {
      float v = oacc1[rr][m];
      v += __shfl_xor(v, 1);
      v += __shfl_xor(v, 2);
      v += __shfl_xor(v, 4);
      v += __shfl_xor(v, 8);
      if (l15 == 0) out[((long)s1 + p0 + pl) * 5 + m] = v + b_out[m];
    }
  }

  const int s2 = (s1 - 1) >> 1;
  const int p02 = p0 >> 1;
  const bool act2 = (wid < 2);
  int xvp2[2];
#pragma unroll
  for (int rr = 0; rr < 2; ++rr) {
    int pl = 8 * wid + 2 * q + rr;
    long pn = (long)s2 + p02 + (act2 ? pl : 0);
    xvp2[rr] = x_id[pn];
  }
  float oacc2[2][5] = {};

  for (int jt = 0; jt < 5; ++jt) {
    const int j0 = jt * 32;
    f32x4 acc[4][2];
#pragma unroll
    for (int g = 0; g < 4; ++g)
#pragma unroll
      for (int jh = 0; jh < 2; ++jh) acc[g][jh] = zero4();

    for (int kk = 0; kk < HP; kk += 32) {
#pragma unroll
      for (int i = 0; i < 2; ++i) {
        int ch = tid + 256 * i;
        int cidx = ch >> 2, kc = (ch & 3) * 8;
        int g = cidx >> 5, jj = cidx & 31;
        int col = g * HP + j0 + jj;
        *(f16x8*)&B_sh[cidx * 40 + kc] = *(const f16x8*)&UreT[col * HP + kk + kc];
      }
      __syncthreads();
      if (act2) {
        f16x8 af = *(const f16x8*)&A2_sh[(16 * wid + l15) * AST + kk + q * 8];
#pragma unroll
        for (int g = 0; g < 4; ++g)
#pragma unroll
          for (int jh = 0; jh < 2; ++jh) {
            f16x8 bfr = *(const f16x8*)&B_sh[(g * 32 + jh * 16 + l15) * 40 + q * 8];
            acc[g][jh] = __builtin_amdgcn_mfma_f32_16x16x32_f16(af, bfr, acc[g][jh], 0, 0, 0);
          }
      }
      __syncthreads();
    }

    if (act2) {
#pragma unroll
      for (int rr = 0; rr < 2; ++rr) {
        const int r = rr * 2;
        const int lr0 = 16 * wid + q * 4 + r;
        const int pl = lr0 >> 1;
        const f16_t* Prp = P + (long)xvp2[rr] * NCOL;
#pragma unroll
        for (int jh = 0; jh < 2; ++jh) {
          const int j = j0 + jh * 16 + l15;
          f16x4 pp = *(const f16x4*)&Prp[j * 4];
          float ipre = (float)pp[0] + acc[0][jh][r] + acc[0][jh][r + 1];
          float opre = (float)pp[1] + acc[1][jh][r] + acc[1][jh][r + 1];
          float upre = (float)pp[2] + acc[2][jh][r] + acc[2][jh][r + 1];
          float pf   = (float)pp[3];
          float fl = sigf(pf + acc[3][jh][r]);
          float fr = sigf(pf + acc[3][jh][r + 1]);
          float clv = (float)C_sh[lr0 * 160 + j];
          float crv = (float)C_sh[(lr0 + 1) * 160 + j];
          float cn = sigf(ipre) * tanhf_(upre) + fl * clv + fr * crv;
          float hn = sigf(opre) * tanhf_(cn);
          Hout[(long)(p02 + pl) * HP + j] = (f16_t)hn;
          Cout[(long)(p02 + pl) * HP + j] = (f16_t)cn;
          int wbase = (j < 150) ? j * 5 : 0;
#pragma unroll
          for (int m = 0; m < 5; ++m) oacc2[rr][m] += hn * W_out[wbase + m];
        }
      }
    }
  }

  if (act2) {
#pragma unroll
    for (int rr = 0; rr < 2; ++rr) {
      int pl = 8 * wid + 2 * q + rr;
#pragma unroll
      for (int m = 0; m < 5; ++m) {
        float v = oacc2[rr][m];
        v += __shfl_xor(v, 1);
        v += __shfl_xor(v, 2);
        v += __shfl_xor(v, 4);
        v += __shfl_xor(v, 8);
        if (l15 == 0) out[((long)s2 + p02 + pl) * 5 + m] = v + b_out[m];
      }
    }
  }
}

// ---------------- single-level tile for the tail (unchanged, proven) -------
__device__ __forceinline__ void level_tile(
    const int* __restrict__ x_id, const f16_t* __restrict__ P,
    const f16_t* __restrict__ UreT, const f16_t* __restrict__ h_child,
    const f16_t* __restrict__ c_child, f16_t* __restrict__ h_par,
    f16_t* __restrict__ c_par, const float* Wo, const float* __restrict__ b_out,
    float* __restrict__ out, int s, int M, int p0, f16_t* A_sh, f16_t* B_sh) {
  const int tid = threadIdx.x;
  const int wid = tid >> 6, lane = tid & 63, l15 = lane & 15, q = lane >> 4;
  int rowsValid = 2 * M - 2 * p0;
  if (rowsValid > 64) rowsValid = 64;

#pragma unroll
  for (int i = 0; i < 5; ++i) {
    int ch = tid + 256 * i;
    int r = ch / 20, kc = (ch % 20) * 8;
    f16x8 v;
    if (r < rowsValid) v = *(const f16x8*)&h_child[(long)(2 * p0 + r) * HP + kc];
    else v = zero8();
    *(f16x8*)&A_sh[r * 184 + kc] = v;
  }
  __syncthreads();

  int xvp[2]; long pnode[2]; int plg[2]; bool valid[2]; int lr0v[2];
#pragma unroll
  for (int rr = 0; rr < 2; ++rr) {
    int lr0 = 16 * wid + q * 4 + rr * 2;
    int pl = lr0 >> 1;
    valid[rr] = (p0 + pl) < M;
    long pn = (long)s + p0 + (valid[rr] ? pl : 0);
    pnode[rr] = pn; plg[rr] = p0 + pl; lr0v[rr] = lr0;
    xvp[rr] = x_id[pn];
  }

  float oacc[2][5];
#pragma unroll
  for (int rr = 0; rr < 2; ++rr)
#pragma unroll
    for (int m = 0; m < 5; ++m) oacc[rr][m] = 0.0f;

  for (int jt = 0; jt < 5; ++jt) {
    const int j0 = jt * 32;
    f32x4 acc[4][2];
#pragma unroll
    for (int g = 0; g < 4; ++g)
#pragma unroll
      for (int jh = 0; jh < 2; ++jh) acc[g][jh] = zero4();

    for (int kk = 0; kk < HP; kk += 32) {
#pragma unroll
      for (int i = 0; i < 2; ++i) {
        int ch = tid + 256 * i;
        int cidx = ch >> 2, kc = (ch & 3) * 8;
        int g = cidx >> 5, jj = cidx & 31;
        int col = g * HP + j0 + jj;
        *(f16x8*)&B_sh[cidx * 40 + kc] = *(const f16x8*)&UreT[col * HP + kk + kc];
      }
      __syncthreads();
      f16x8 af = *(const f16x8*)&A_sh[(16 * wid + l15) * 184 + kk + q * 8];
#pragma unroll
      for (int g = 0; g < 4; ++g)
#pragma unroll
        for (int jh = 0; jh < 2; ++jh) {
          f16x8 bfr = *(const f16x8*)&B_sh[(g * 32 + jh * 16 + l15) * 40 + q * 8];
          acc[g][jh] = __builtin_amdgcn_mfma_f32_16x16x32_f16(af, bfr, acc[g][jh], 0, 0, 0);
        }
      __syncthreads();
    }

#pragma unroll
    for (int rr = 0; rr < 2; ++rr) {
      const int r = rr * 2;
      const f16_t* Prp = P + (long)xvp[rr] * NCOL;
#pragma unroll
      for (int jh = 0; jh < 2; ++jh) {
        const int j = j0 + jh * 16 + l15;
        f16x4 pp = *(const f16x4*)&Prp[j * 4];
        float ipre = (float)pp[0] + acc[0][jh][r] + acc[0][jh][r + 1];
        float opre = (float)pp[1] + acc[1][jh][r] + acc[1][jh][r + 1];
        float upre = (float)pp[2] + acc[2][jh][r] + acc[2][jh][r + 1];
        float pf   = (float)pp[3];
        float fl = sigf(pf + acc[3][jh][r]);
        float fr = sigf(pf + acc[3][jh][r + 1]);
        float clv = valid[rr] ? (float)c_child[(long)(2 * p0 + lr0v[rr]) * HP + j] : 0.0f;
        float crv = valid[rr] ? (float)c_child[(long)(2 * p0 + lr0v[rr] + 1) * HP + j] : 0.0f;
        float cn = sigf(ipre) * tanhf_(upre) + fl * clv + fr * crv;
        float hn = sigf(opre) * tanhf_(cn);
        if (valid[rr]) {
          h_par[(long)plg[rr] * HP + j] = (f16_t)hn;
          c_par[(long)plg[rr] * HP + j] = (f16_t)cn;
        }
#pragma unroll
        for (int m = 0; m < 5; ++m) oacc[rr][m] += hn * Wo[j * 5 + m];
      }
    }
  }

#pragma unroll
  for (int rr = 0; rr < 2; ++rr) {
#pragma unroll
    for (int m = 0; m < 5; ++m) {
      float v = oacc[rr][m];
      v += __shfl_xor(v, 1);
      v += __shfl_xor(v, 2);
      v += __shfl_xor(v, 4);
      v += __shfl_xor(v, 8);
      if (l15 == 0 && valid[rr]) out[pnode[rr] * 5 + m] = v + b_out[m];
    }
  }
}

// Levels 4..0 (children: L5 in HA/CA): one block, barriers between levels.
__global__ __launch_bounds__(256, 4) void tail_kernel(
    const int* __restrict__ x_id, const f16_t* __restrict__ P,
    const f16_t* __restrict__ UreT, f16_t* __restrict__ HA, f16_t* __restrict__ HB,
    f16_t* __restrict__ CA, f16_t* __restrict__ CB, const float* __restrict__ W_out,
    const float* __restrict__ b_out, float* __restrict__ out) {
  __shared__ __align__(16) f16_t A_sh[64 * 184];
  __shared__ __align__(16) f16_t B_sh[128 * 40];
  __shared__ float Wo[800];
  for (int i = threadIdx.x; i < 800; i += 256) Wo[i] = (i < 750) ? W_out[i] : 0.0f;
  for (int lvl = 4; lvl >= 0; --lvl) {
    int s = (1 << lvl) - 1, M = 1 << lvl;
    const f16_t* hc = ((lvl + 1) & 1) ? HA : HB;
    const f16_t* cc = ((lvl + 1) & 1) ? CA : CB;
    f16_t* hp = (lvl & 1) ? HA : HB;
    f16_t* cp = (lvl & 1) ? CA : CB;
    level_tile(x_id, P, UreT, hc, cc, hp, cp, Wo, b_out, out, s, M, 0, A_sh, B_sh);
    __syncthreads();
  }
}

extern "C" void kernel_launch(void* const* d_in, const int* in_sizes, int n_in,
                              void* d_out, int out_size, void* d_ws, size_t ws_size,
                              hipStream_t stream) {
  const int* x_id   = (const int*)d_in[0];
  const float* emb  = (const float*)d_in[1];
  const float* W_iou = (const float*)d_in[2];
  const float* U_iou = (const float*)d_in[3];
  const float* b_iou = (const float*)d_in[4];
  const float* W_f   = (const float*)d_in[5];
  const float* U_f   = (const float*)d_in[6];
  const float* b_f   = (const float*)d_in[7];
  const float* W_out = (const float*)d_in[8];
  const float* b_out = (const float*)d_in[9];
  float* out = (float*)d_out;
  char* ws = (char*)d_ws;

  // workspace carve (bytes), peak 180,503,040 <= 182,103,040 budget.
  // All region reuses are stream-ordered (writer launched after last reader).
  f16_t* WreT  = (f16_t*)(ws + 0);              // 409,600
  f16_t* UreT  = (f16_t*)(ws + 409600);         // 204,800
  float* bre   = (float*)(ws + 614400);         // 2,560
  f16_t* P     = (f16_t*)(ws + 616960);         // 64,000,000 (persistent)
  f16_t* Hleaf = (f16_t*)(ws + 64616960);       // 16,000,000 (dead after L17)
  f16_t* Cleaf = (f16_t*)(ws + 80616960);       // 16,000,000 (dead after L17)
  float* Oleaf = (float*)(ws + 96616960);       // 1,600,000 (dead after leafout)
  f16_t* H17   = (f16_t*)(ws + 96616960);       // 41,943,040 (131072 rows)
  f16_t* C17   = (f16_t*)(ws + 138560000);      // 41,943,040 -> ends 180,503,040
  f16_t* H15 = (f16_t*)(ws + 64616960);         // 10,485,760 (32768 rows) over Hleaf
  f16_t* C15 = (f16_t*)(ws + 75102720);         // 10,485,760
  f16_t* H13 = (f16_t*)(ws + 96616960);         //  2,621,440 (8192 rows) over H17
  f16_t* C13 = (f16_t*)(ws + 99238400);         //  2,621,440
  f16_t* H11 = (f16_t*)(ws + 64616960);         //    655,360 (2048 rows) over H15
  f16_t* C11 = (f16_t*)(ws + 65272320);         //    655,360
  f16_t* H9  = (f16_t*)(ws + 96616960);         //    163,840 (512 rows) over H13
  f16_t* C9  = (f16_t*)(ws + 96780800);         //    163,840
  f16_t* H7  = (f16_t*)(ws + 64616960);         //     40,960 (128 rows) over H11
  f16_t* C7  = (f16_t*)(ws + 64657920);         //     40,960
  f16_t* H5  = (f16_t*)(ws + 96616960);         //     10,240 (32 rows) over H9
  f16_t* C5  = (f16_t*)(ws + 96627200);         //     10,240
  f16_t* HSc = (f16_t*)(ws + 64616960);         // tail scratch (over H7, dead)
  f16_t* CSc = (f16_t*)(ws + 64627200);         // tail scratch

  prep_params<<<1203, 256, 0, stream>>>(W_iou, U_iou, b_iou, W_f, U_f, b_f, WreT, UreT, bre);
  gemm_p<<<782, 256, 0, stream>>>(emb, WreT, bre, P);
  leafhc_kernel<<<15625, 256, 0, stream>>>(P, Hleaf, Cleaf);
  oleaf_kernel<<<3125, 256, 0, stream>>>(Hleaf, W_out, b_out, Oleaf);
  leafout_kernel<<<1024, 256, 0, stream>>>(x_id, Oleaf, out);

  // level 17: big-M tile (128 leaves -> 64 parents/block), 2048 blocks
  level17b_kernel<<<2048, 256, 0, stream>>>(x_id, P, UreT, Hleaf, Cleaf, H17, C17,
                                            W_out, b_out, out);
  // fused pairs (round-3 proven):
  fused_kernel<false><<<2048, 256, 0, stream>>>(x_id, P, UreT, H17, C17, H15, C15,
                                                W_out, b_out, out, (1 << 16) - 1, 1 << 16);
  fused_kernel<false><<<512, 256, 0, stream>>>(x_id, P, UreT, H15, C15, H13, C13,
                                               W_out, b_out, out, (1 << 14) - 1, 1 << 14);
  fused_kernel<false><<<128, 256, 0, stream>>>(x_id, P, UreT, H13, C13, H11, C11,
                                               W_out, b_out, out, (1 << 12) - 1, 1 << 12);
  fused_kernel<false><<<32, 256, 0, stream>>>(x_id, P, UreT, H11, C11, H9, C9,
                                              W_out, b_out, out, (1 << 10) - 1, 1 << 10);
  fused_kernel<false><<<8, 256, 0, stream>>>(x_id, P, UreT, H9, C9, H7, C7,
                                             W_out, b_out, out, (1 << 8) - 1, 1 << 8);
  fused_kernel<false><<<2, 256, 0, stream>>>(x_id, P, UreT, H7, C7, H5, C5,
                                             W_out, b_out, out, (1 << 6) - 1, 1 << 6);
  // levels 4..0 (L5 children sit in H5/C5)
  tail_kernel<<<1, 256, 0, stream>>>(x_id, P, UreT, H5, HSc, C5, CSc, W_out, b_out, out);

  (void)in_sizes; (void)n_in; (void)out_size; (void)ws_size;
}